// Round 1
// baseline (2870.936 us; speedup 1.0000x reference)
//
#include <hip/hip_runtime.h>
#include <cfloat>

// VQ-VAE vector quantizer, fp32 baseline (round 1: correctness + counters).
// N=32768 rows, K=8192 codes, D=256.
#define K_CODES 8192
#define DIM     256
#define NROWS   32768
#define DECAYF  0.99f
#define OMD     0.01f
#define EPSF    1e-5f

// d_out float offsets (outputs concatenated in reference return order)
#define O_ZQ    0
#define O_LOSS  8388608
#define O_IDX   8388609
#define O_NEMB  8421377
#define O_NCS   10518529
#define O_NEMAW 10526721

// ---------------------------------------------------------------- eSq + zero
// one wave per code row: |e_k|^2 ; also zero counts/loss/ntot scratch (8194 floats)
__global__ void k_esq_zero(const float* __restrict__ emb,
                           float* __restrict__ esq,
                           float* __restrict__ zbuf) {
    const int gid  = blockIdx.x * blockDim.x + threadIdx.x;
    if (gid < K_CODES + 2) zbuf[gid] = 0.0f;
    const int code = gid >> 6;
    const int lane = gid & 63;
    float4 v = ((const float4*)emb)[code * 64 + lane];
    float s = fmaf(v.x, v.x, fmaf(v.y, v.y, fmaf(v.z, v.z, v.w * v.w)));
#pragma unroll
    for (int off = 32; off > 0; off >>= 1) s += __shfl_down(s, off, 64);
    if (lane == 0) esq[code] = s;
}

// ---------------------------------------------------------------- init new_ema_w
__global__ void k_init_nemaw(const float* __restrict__ ema_w, float* __restrict__ out) {
    const int i = blockIdx.x * blockDim.x + threadIdx.x;  // float4 index, 524288 total
    float4 v = ((const float4*)ema_w)[i];
    ((float4*)out)[i] = make_float4(DECAYF * v.x, DECAYF * v.y, DECAYF * v.z, DECAYF * v.w);
}

// ---------------------------------------------------------------- fused GEMM+argmin
// score(n,k) = |e_k|^2 - 2 z_n.e_k   (|z|^2 constant per row -> dropped)
// Block: 256 threads (tx=t&15 codes, ty=t>>4 rows), per-thread 4 rows x 8 codes.
// Tile: BM=64 rows x BN=128 codes, D chunked by 32. All LDS reads are b128;
// code assignment tx+16*j makes b-side bank quads (9*c mod 8)=c mod 8 -> <=2-way (free).
#define BM   64
#define BN   128
#define BD   32
#define LSTR 36   // padded row stride in floats; 36*4=144B, %16==0 -> b128-aligned

__global__ __launch_bounds__(256, 2) void k_argmin(
        const float* __restrict__ z, const float* __restrict__ emb,
        const float* __restrict__ esq,
        int* __restrict__ idx_i, float* __restrict__ idx_f) {
    __shared__ float z_s[BM * LSTR];   //  9216 B
    __shared__ float e_s[BN * LSTR];   // 18432 B  (27.6 KB total)
    const int t    = threadIdx.x;
    const int tx   = t & 15;
    const int ty   = t >> 4;
    const int row0 = blockIdx.x * BM;

    float best[4]; int bidx[4];
#pragma unroll
    for (int r = 0; r < 4; ++r) { best[r] = FLT_MAX; bidx[r] = 0; }

    for (int k0 = 0; k0 < K_CODES; k0 += BN) {
        float acc[4][8];
#pragma unroll
        for (int r = 0; r < 4; ++r)
#pragma unroll
            for (int c = 0; c < 8; ++c) acc[r][c] = 0.0f;

        for (int d0 = 0; d0 < DIM; d0 += BD) {
            __syncthreads();   // guard LDS overwrite vs previous chunk's readers
            // z chunk: 64 rows x 32 d = 512 float4, 2/thread
#pragma unroll
            for (int i = 0; i < 2; ++i) {
                int f  = i * 256 + t;
                int r  = f >> 3;
                int c4 = (f & 7) << 2;
                float4 v = *(const float4*)(z + (size_t)(row0 + r) * DIM + d0 + c4);
                *(float4*)&z_s[r * LSTR + c4] = v;
            }
            // e chunk: 128 codes x 32 d = 1024 float4, 4/thread
#pragma unroll
            for (int i = 0; i < 4; ++i) {
                int f  = i * 256 + t;
                int c  = f >> 3;
                int c4 = (f & 7) << 2;
                float4 v = *(const float4*)(emb + (size_t)(k0 + c) * DIM + d0 + c4);
                *(float4*)&e_s[c * LSTR + c4] = v;
            }
            __syncthreads();
#pragma unroll
            for (int dd = 0; dd < BD; dd += 4) {
                float4 a[4], b[8];
#pragma unroll
                for (int j = 0; j < 4; ++j)
                    a[j] = *(const float4*)&z_s[(ty * 4 + j) * LSTR + dd];
#pragma unroll
                for (int j = 0; j < 8; ++j)
                    b[j] = *(const float4*)&e_s[(tx + 16 * j) * LSTR + dd];
#pragma unroll
                for (int r = 0; r < 4; ++r)
#pragma unroll
                    for (int c = 0; c < 8; ++c) {
                        acc[r][c] = fmaf(a[r].x, b[c].x, acc[r][c]);
                        acc[r][c] = fmaf(a[r].y, b[c].y, acc[r][c]);
                        acc[r][c] = fmaf(a[r].z, b[c].z, acc[r][c]);
                        acc[r][c] = fmaf(a[r].w, b[c].w, acc[r][c]);
                    }
            }
        }
        // argmin update for this k-tile (first-min-index tie-break)
#pragma unroll
        for (int c = 0; c < 8; ++c) {
            const int code = k0 + tx + 16 * c;
            const float es = esq[code];
#pragma unroll
            for (int r = 0; r < 4; ++r) {
                float s = fmaf(-2.0f, acc[r][c], es);
                if (s < best[r] || (s == best[r] && code < bidx[r])) {
                    best[r] = s; bidx[r] = code;
                }
            }
        }
    }
    // cross-thread (16 tx) per-row reduction; reuse tile LDS
    __syncthreads();
    float* rv = e_s;          // 64*16 floats
    int*   ri = (int*)z_s;    // 64*16 ints
#pragma unroll
    for (int r = 0; r < 4; ++r) {
        rv[(ty * 4 + r) * 16 + tx] = best[r];
        ri[(ty * 4 + r) * 16 + tx] = bidx[r];
    }
    __syncthreads();
    if (t < 64) {
        float m = rv[t * 16]; int mi = ri[t * 16];
#pragma unroll
        for (int i = 1; i < 16; ++i) {
            float v = rv[t * 16 + i]; int vi = ri[t * 16 + i];
            if (v < m || (v == m && vi < mi)) { m = v; mi = vi; }
        }
        idx_i[row0 + t] = mi;
        idx_f[row0 + t] = (float)mi;
    }
}

// ---------------------------------------------------------------- gather + loss + EMA scatter
// one wave per z-row (64 lanes x float4 = 256 = D)
__global__ void k_gather(const float* __restrict__ z, const float* __restrict__ emb,
                         const int* __restrict__ idx_i,
                         float* __restrict__ zq, float* __restrict__ nemaw,
                         float* __restrict__ counts, float* __restrict__ loss) {
    const int gid  = blockIdx.x * blockDim.x + threadIdx.x;
    const int row  = gid >> 6;
    const int lane = gid & 63;
    const int code = idx_i[row];
    float4 zv = ((const float4*)z)[row * 64 + lane];
    float4 ev = ((const float4*)emb)[(size_t)code * 64 + lane];
    // straight-through: z + (z_q - z), matching reference rounding
    float4 o = make_float4(zv.x + (ev.x - zv.x), zv.y + (ev.y - zv.y),
                           zv.z + (ev.z - zv.z), zv.w + (ev.w - zv.w));
    ((float4*)zq)[row * 64 + lane] = o;
    float dx = ev.x - zv.x, dy = ev.y - zv.y, dz = ev.z - zv.z, dw = ev.w - zv.w;
    float s = fmaf(dx, dx, fmaf(dy, dy, fmaf(dz, dz, dw * dw)));
#pragma unroll
    for (int off = 32; off > 0; off >>= 1) s += __shfl_down(s, off, 64);
    if (lane == 0) { atomicAdd(loss, s); atomicAdd(&counts[code], 1.0f); }
    float* base = nemaw + (size_t)code * DIM + lane * 4;
    atomicAdd(base + 0, OMD * zv.x);
    atomicAdd(base + 1, OMD * zv.y);
    atomicAdd(base + 2, OMD * zv.z);
    atomicAdd(base + 3, OMD * zv.w);
}

// ---------------------------------------------------------------- new_cluster_size, n, loss
__global__ void k_ncs(const float* __restrict__ ema_cs, const float* __restrict__ counts,
                      float* __restrict__ ncs_out, float* __restrict__ ntot,
                      const float* __restrict__ loss_in, float* __restrict__ loss_out) {
    __shared__ float red[16];
    const int t = threadIdx.x;
    float s = 0.0f;
    for (int i = t; i < K_CODES; i += 1024) {
        float v = fmaf(DECAYF, ema_cs[i], OMD * counts[i]);
        ncs_out[i] = v;
        s += v;
    }
#pragma unroll
    for (int off = 32; off > 0; off >>= 1) s += __shfl_down(s, off, 64);
    if ((t & 63) == 0) red[t >> 6] = s;
    __syncthreads();
    if (t < 16) {
        float v = red[t];
#pragma unroll
        for (int off = 8; off > 0; off >>= 1) v += __shfl_down(v, off, 16);
        if (t == 0) {
            *ntot = v;
            *loss_out = 0.25f * (*loss_in) / 8388608.0f;  // COMMITMENT_COST * mean
        }
    }
}

// ---------------------------------------------------------------- new_embedding
__global__ void k_nemb(const float* __restrict__ nemaw, const float* __restrict__ ncs,
                       const float* __restrict__ ntot_p, float* __restrict__ nemb) {
    const int i4 = blockIdx.x * blockDim.x + threadIdx.x;  // float4 idx, 524288 total
    const int k  = i4 >> 6;
    const float n   = *ntot_p;
    const float inv = n / (n + (float)K_CODES * EPSF);
    const float cs  = (ncs[k] + EPSF) * inv;
    float4 w = ((const float4*)nemaw)[i4];
    ((float4*)nemb)[i4] = make_float4(w.x / cs, w.y / cs, w.z / cs, w.w / cs);
}

extern "C" void kernel_launch(void* const* d_in, const int* in_sizes, int n_in,
                              void* d_out, int out_size, void* d_ws, size_t ws_size,
                              hipStream_t stream) {
    const float* z      = (const float*)d_in[0];
    const float* emb    = (const float*)d_in[1];
    const float* ema_cs = (const float*)d_in[2];
    const float* ema_w  = (const float*)d_in[3];
    float* out = (float*)d_out;

    // workspace layout (196,616 B total; re-poisoned each call -> re-init here)
    int*   ws_idx    = (int*)d_ws;                    // [32768]
    float* ws_counts = (float*)d_ws + NROWS;          // [8192]
    float* ws_loss   = ws_counts + K_CODES;           // [1]
    float* ws_ntot   = ws_loss + 1;                   // [1]
    float* ws_esq    = ws_ntot + 1;                   // [8192]

    k_esq_zero  <<<2048, 256, 0, stream>>>(emb, ws_esq, ws_counts);
    k_init_nemaw<<<2048, 256, 0, stream>>>(ema_w, out + O_NEMAW);
    k_argmin    <<<NROWS / BM, 256, 0, stream>>>(z, emb, ws_esq, ws_idx, out + O_IDX);
    k_gather    <<<NROWS / 4, 256, 0, stream>>>(z, emb, ws_idx, out + O_ZQ,
                                                out + O_NEMAW, ws_counts, ws_loss);
    k_ncs       <<<1, 1024, 0, stream>>>(ema_cs, ws_counts, out + O_NCS, ws_ntot,
                                         ws_loss, out + O_LOSS);
    k_nemb      <<<2048, 256, 0, stream>>>(out + O_NEMAW, out + O_NCS, ws_ntot,
                                           out + O_NEMB);
}

// Round 2
// 1254.246 us; speedup vs baseline: 2.2890x; 2.2890x over previous
//
#include <hip/hip_runtime.h>
#include <cfloat>

// VQ-VAE vector quantizer. Round 2: bf16 hi/lo split MFMA argmin-GEMM.
// N=32768 rows, K=8192 codes, D=256.
#define K_CODES 8192
#define DIM     256
#define NROWS   32768
#define DECAYF  0.99f
#define OMD     0.01f
#define EPSF    1e-5f

// d_out float offsets (outputs concatenated in reference return order)
#define O_ZQ    0
#define O_LOSS  8388608
#define O_IDX   8388609
#define O_NEMB  8421377
#define O_NCS   10518529
#define O_NEMAW 10526721

// ---- MFMA path params
#define NCH          8                    // code chunks (occupancy/packing)
#define CODES_PER_CH (K_CODES / NCH)      // 1024
#define BM_M         128                  // rows per block
#define BN_M         128                  // codes per N-tile
#define BK_M         32

typedef __attribute__((ext_vector_type(8))) short short8;
typedef __attribute__((ext_vector_type(4))) float floatx4;

__device__ __forceinline__ unsigned short f2bf_rne(float x) {
    unsigned u = __float_as_uint(x);
    u += 0x7fffu + ((u >> 16) & 1u);
    return (unsigned short)(u >> 16);
}
__device__ __forceinline__ float bf2f(unsigned short h) {
    return __uint_as_float(((unsigned)h) << 16);
}
__device__ __forceinline__ void async16(const void* g, void* l) {
    __builtin_amdgcn_global_load_lds(
        (const __attribute__((address_space(1))) void*)g,
        (__attribute__((address_space(3))) void*)l, 16, 0, 0);
}

// ---------------------------------------------------------------- z -> bf16 hi/lo
__global__ void k_cvt_z(const float* __restrict__ z,
                        unsigned short* __restrict__ zhi,
                        unsigned short* __restrict__ zlo) {
    const int i = blockIdx.x * blockDim.x + threadIdx.x;   // float4 idx, 2,097,152
    float4 v = ((const float4*)z)[i];
    ushort4 h, l;
    h.x = f2bf_rne(v.x); l.x = f2bf_rne(v.x - bf2f(h.x));
    h.y = f2bf_rne(v.y); l.y = f2bf_rne(v.y - bf2f(h.y));
    h.z = f2bf_rne(v.z); l.z = f2bf_rne(v.z - bf2f(h.z));
    h.w = f2bf_rne(v.w); l.w = f2bf_rne(v.w - bf2f(h.w));
    ((ushort4*)zhi)[i] = h;
    ((ushort4*)zlo)[i] = l;
}

// ---------------------------------------------------------------- emb -> bf16 hi/lo + |e|^2 + zero scratch
// one wave per code row; zbuf zeroes counts/loss/ntot (8194 floats)
__global__ void k_cvt_e(const float* __restrict__ emb,
                        unsigned short* __restrict__ ehi,
                        unsigned short* __restrict__ elo,
                        float* __restrict__ esq,
                        float* __restrict__ zbuf) {
    const int gid  = blockIdx.x * blockDim.x + threadIdx.x;
    if (gid < K_CODES + 2) zbuf[gid] = 0.0f;
    const int code = gid >> 6;
    const int lane = gid & 63;
    float4 v = ((const float4*)emb)[code * 64 + lane];
    ushort4 h, l;
    h.x = f2bf_rne(v.x); l.x = f2bf_rne(v.x - bf2f(h.x));
    h.y = f2bf_rne(v.y); l.y = f2bf_rne(v.y - bf2f(h.y));
    h.z = f2bf_rne(v.z); l.z = f2bf_rne(v.z - bf2f(h.z));
    h.w = f2bf_rne(v.w); l.w = f2bf_rne(v.w - bf2f(h.w));
    ((ushort4*)ehi)[code * 64 + lane] = h;
    ((ushort4*)elo)[code * 64 + lane] = l;
    float s = fmaf(v.x, v.x, fmaf(v.y, v.y, fmaf(v.z, v.z, v.w * v.w)));
#pragma unroll
    for (int off = 32; off > 0; off >>= 1) s += __shfl_down(s, off, 64);
    if (lane == 0) esq[code] = s;
}

// ---------------------------------------------------------------- init new_ema_w
__global__ void k_init_nemaw(const float* __restrict__ ema_w, float* __restrict__ out) {
    const int i = blockIdx.x * blockDim.x + threadIdx.x;  // float4 idx, 524288
    float4 v = ((const float4*)ema_w)[i];
    ((float4*)out)[i] = make_float4(DECAYF * v.x, DECAYF * v.y, DECAYF * v.z, DECAYF * v.w);
}

// ---------------------------------------------------------------- MFMA argmin GEMM
// score(n,k) = |e_k|^2 - 2 z_n.e_k ; z.e = zhi.ehi + zhi.elo + zlo.ehi (eff K=768)
// Block 256 = 4 waves; wave w: rows wrow=(w>>1)*64, cols wcol=(w&1)*64; acc 4x4 of 16x16x32.
// Staging: global_load_lds width=16, row-major [row][32] bf16 tiles (no pad - m104 caveat).
__global__ __launch_bounds__(256) void k_argmin_mfma(
        const unsigned short* __restrict__ zhi, const unsigned short* __restrict__ zlo,
        const unsigned short* __restrict__ ehi, const unsigned short* __restrict__ elo,
        const float* __restrict__ esq,
        float* __restrict__ part_v, int* __restrict__ part_i) {
    __shared__ __align__(16) unsigned short a_s[BM_M * BK_M];  // 8 KB
    __shared__ __align__(16) unsigned short b_s[BN_M * BK_M];  // 8 KB
    const int t    = threadIdx.x;
    const int w    = t >> 6;
    const int lane = t & 63;
    const int quad = lane >> 4;
    const int m    = lane & 15;
    const int wrow = (w >> 1) * 64;
    const int wcol = (w & 1) * 64;
    const int row0   = blockIdx.x * BM_M;
    const int cbase0 = blockIdx.y * CODES_PER_CH;
    // staging lane geometry: lane covers row (lane>>2) of a 16-row chunk, 8 bf16 at (lane&3)*8
    const int srow = lane >> 2;
    const int sk   = (lane & 3) * 8;

    float best_v[16]; int best_i[16];
#pragma unroll
    for (int r = 0; r < 16; ++r) { best_v[r] = FLT_MAX; best_i[r] = 0; }

    const unsigned short* const Asrc[3] = { zhi, zhi, zlo };
    const unsigned short* const Bsrc[3] = { ehi, elo, ehi };

    for (int nt = 0; nt < CODES_PER_CH / BN_M; ++nt) {
        const int cb = cbase0 + nt * BN_M;
        floatx4 acc[4][4];
#pragma unroll
        for (int i = 0; i < 4; ++i)
#pragma unroll
            for (int j = 0; j < 4; ++j) acc[i][j] = (floatx4){0.f, 0.f, 0.f, 0.f};

        for (int seg = 0; seg < 3; ++seg) {
            const unsigned short* As = Asrc[seg];
            const unsigned short* Bs = Bsrc[seg];
            for (int k0 = 0; k0 < DIM; k0 += BK_M) {
                __syncthreads();   // previous iter's ds_reads done before overwrite
                if (w < 2) {       // waves 0,1 stage A (128x32), 4x 1KB chunks each
#pragma unroll
                    for (int c = 0; c < 4; ++c) {
                        const int q = w * 4 + c;
                        async16(As + (size_t)(row0 + q * 16 + srow) * DIM + k0 + sk,
                                &a_s[q * 512]);
                    }
                } else {           // waves 2,3 stage B
#pragma unroll
                    for (int c = 0; c < 4; ++c) {
                        const int q = (w - 2) * 4 + c;
                        async16(Bs + (size_t)(cb + q * 16 + srow) * DIM + k0 + sk,
                                &b_s[q * 512]);
                    }
                }
                __syncthreads();   // barrier waits vmcnt(0): staged data visible
                short8 af[4], bfr[4];
#pragma unroll
                for (int i = 0; i < 4; ++i)
                    af[i] = *(const short8*)&a_s[(wrow + i * 16 + m) * BK_M + quad * 8];
#pragma unroll
                for (int j = 0; j < 4; ++j)
                    bfr[j] = *(const short8*)&b_s[(wcol + j * 16 + m) * BK_M + quad * 8];
#pragma unroll
                for (int i = 0; i < 4; ++i)
#pragma unroll
                    for (int j = 0; j < 4; ++j)
                        acc[i][j] = __builtin_amdgcn_mfma_f32_16x16x32_bf16(
                            af[i], bfr[j], acc[i][j], 0, 0, 0);
            }
        }
        // epilogue: lane owns rows wrow+i*16+quad*4+reg, col wcol+j*16+m of this tile.
        // codes ascend in (nt, j) for fixed lane -> strict < keeps first-min.
#pragma unroll
        for (int j = 0; j < 4; ++j) {
            const int code = cb + wcol + j * 16 + m;
            const float es = esq[code];
#pragma unroll
            for (int i = 0; i < 4; ++i)
#pragma unroll
                for (int reg = 0; reg < 4; ++reg) {
                    const float s = fmaf(-2.0f, acc[i][j][reg], es);
                    const int r = i * 4 + reg;
                    if (s < best_v[r]) { best_v[r] = s; best_i[r] = code; }
                }
        }
    }
    // butterfly across the 16 lanes (same quad) sharing each row
#pragma unroll
    for (int r = 0; r < 16; ++r) {
        float v = best_v[r]; int bi = best_i[r];
#pragma unroll
        for (int off = 1; off < 16; off <<= 1) {
            const float ov = __shfl_xor(v, off, 64);
            const int   oi = __shfl_xor(bi, off, 64);
            if (ov < v || (ov == v && oi < bi)) { v = ov; bi = oi; }
        }
        best_v[r] = v; best_i[r] = bi;
    }
    __syncthreads();               // done with staging LDS; reuse for reduction
    float* redv = (float*)a_s;     // [128][2]
    int*   redi = (int*)b_s;       // [128][2]
    if (m == 0) {
#pragma unroll
        for (int r = 0; r < 16; ++r) {
            const int row = wrow + (r >> 2) * 16 + quad * 4 + (r & 3);
            redv[row * 2 + (w & 1)] = best_v[r];
            redi[row * 2 + (w & 1)] = best_i[r];
        }
    }
    __syncthreads();
    if (t < 128) {
        const float v0 = redv[t * 2], v1 = redv[t * 2 + 1];
        const int   i0 = redi[t * 2], i1 = redi[t * 2 + 1];
        const bool  b1 = (v1 < v0) || (v1 == v0 && i1 < i0);
        const size_t o = (size_t)blockIdx.y * NROWS + row0 + t;
        part_v[o] = b1 ? v1 : v0;
        part_i[o] = b1 ? i1 : i0;
    }
}

// ---------------------------------------------------------------- merge chunk partials
__global__ void k_reduce_part(const float* __restrict__ pv, const int* __restrict__ pi,
                              int* __restrict__ idx_i, float* __restrict__ idx_f) {
    const int r = blockIdx.x * blockDim.x + threadIdx.x;
    float v = pv[r]; int bi = pi[r];
    for (int c = 1; c < NCH; ++c) {   // chunks ascend in code range: strict < keeps lowest
        const float v2 = pv[(size_t)c * NROWS + r];
        const int   i2 = pi[(size_t)c * NROWS + r];
        if (v2 < v || (v2 == v && i2 < bi)) { v = v2; bi = i2; }
    }
    idx_i[r] = bi;
    idx_f[r] = (float)bi;
}

// ================================================================ fp32 fallback argmin
// (round-1 verified kernel; used only if ws_size can't hold bf16 scratch)
#define BM   64
#define BN   128
#define BD   32
#define LSTR 36

__global__ void k_esq_zero(const float* __restrict__ emb,
                           float* __restrict__ esq,
                           float* __restrict__ zbuf) {
    const int gid  = blockIdx.x * blockDim.x + threadIdx.x;
    if (gid < K_CODES + 2) zbuf[gid] = 0.0f;
    const int code = gid >> 6;
    const int lane = gid & 63;
    float4 v = ((const float4*)emb)[code * 64 + lane];
    float s = fmaf(v.x, v.x, fmaf(v.y, v.y, fmaf(v.z, v.z, v.w * v.w)));
#pragma unroll
    for (int off = 32; off > 0; off >>= 1) s += __shfl_down(s, off, 64);
    if (lane == 0) esq[code] = s;
}

__global__ __launch_bounds__(256, 2) void k_argmin(
        const float* __restrict__ z, const float* __restrict__ emb,
        const float* __restrict__ esq,
        int* __restrict__ idx_i, float* __restrict__ idx_f) {
    __shared__ float z_s[BM * LSTR];
    __shared__ float e_s[BN * LSTR];
    const int t    = threadIdx.x;
    const int tx   = t & 15;
    const int ty   = t >> 4;
    const int row0 = blockIdx.x * BM;
    float best[4]; int bidx[4];
#pragma unroll
    for (int r = 0; r < 4; ++r) { best[r] = FLT_MAX; bidx[r] = 0; }
    for (int k0 = 0; k0 < K_CODES; k0 += BN) {
        float acc[4][8];
#pragma unroll
        for (int r = 0; r < 4; ++r)
#pragma unroll
            for (int c = 0; c < 8; ++c) acc[r][c] = 0.0f;
        for (int d0 = 0; d0 < DIM; d0 += BD) {
            __syncthreads();
#pragma unroll
            for (int i = 0; i < 2; ++i) {
                int f = i * 256 + t, r = f >> 3, c4 = (f & 7) << 2;
                *(float4*)&z_s[r * LSTR + c4] =
                    *(const float4*)(z + (size_t)(row0 + r) * DIM + d0 + c4);
            }
#pragma unroll
            for (int i = 0; i < 4; ++i) {
                int f = i * 256 + t, c = f >> 3, c4 = (f & 7) << 2;
                *(float4*)&e_s[c * LSTR + c4] =
                    *(const float4*)(emb + (size_t)(k0 + c) * DIM + d0 + c4);
            }
            __syncthreads();
#pragma unroll
            for (int dd = 0; dd < BD; dd += 4) {
                float4 a[4], b[8];
#pragma unroll
                for (int j = 0; j < 4; ++j)
                    a[j] = *(const float4*)&z_s[(ty * 4 + j) * LSTR + dd];
#pragma unroll
                for (int j = 0; j < 8; ++j)
                    b[j] = *(const float4*)&e_s[(tx + 16 * j) * LSTR + dd];
#pragma unroll
                for (int r = 0; r < 4; ++r)
#pragma unroll
                    for (int c = 0; c < 8; ++c) {
                        acc[r][c] = fmaf(a[r].x, b[c].x, acc[r][c]);
                        acc[r][c] = fmaf(a[r].y, b[c].y, acc[r][c]);
                        acc[r][c] = fmaf(a[r].z, b[c].z, acc[r][c]);
                        acc[r][c] = fmaf(a[r].w, b[c].w, acc[r][c]);
                    }
            }
        }
#pragma unroll
        for (int c = 0; c < 8; ++c) {
            const int code = k0 + tx + 16 * c;
            const float es = esq[code];
#pragma unroll
            for (int r = 0; r < 4; ++r) {
                float s = fmaf(-2.0f, acc[r][c], es);
                if (s < best[r] || (s == best[r] && code < bidx[r])) {
                    best[r] = s; bidx[r] = code;
                }
            }
        }
    }
    __syncthreads();
    float* rv = e_s;
    int*   ri = (int*)z_s;
#pragma unroll
    for (int r = 0; r < 4; ++r) {
        rv[(ty * 4 + r) * 16 + tx] = best[r];
        ri[(ty * 4 + r) * 16 + tx] = bidx[r];
    }
    __syncthreads();
    if (t < 64) {
        float mv = rv[t * 16]; int mi = ri[t * 16];
#pragma unroll
        for (int i = 1; i < 16; ++i) {
            float v = rv[t * 16 + i]; int vi = ri[t * 16 + i];
            if (v < mv || (v == mv && vi < mi)) { mv = v; mi = vi; }
        }
        idx_i[row0 + t] = mi;
        idx_f[row0 + t] = (float)mi;
    }
}

// ---------------------------------------------------------------- gather + loss + EMA scatter
__global__ void k_gather(const float* __restrict__ z, const float* __restrict__ emb,
                         const int* __restrict__ idx_i,
                         float* __restrict__ zq, float* __restrict__ nemaw,
                         float* __restrict__ counts, float* __restrict__ loss) {
    const int gid  = blockIdx.x * blockDim.x + threadIdx.x;
    const int row  = gid >> 6;
    const int lane = gid & 63;
    const int code = idx_i[row];
    float4 zv = ((const float4*)z)[row * 64 + lane];
    float4 ev = ((const float4*)emb)[(size_t)code * 64 + lane];
    float4 o = make_float4(zv.x + (ev.x - zv.x), zv.y + (ev.y - zv.y),
                           zv.z + (ev.z - zv.z), zv.w + (ev.w - zv.w));
    ((float4*)zq)[row * 64 + lane] = o;
    float dx = ev.x - zv.x, dy = ev.y - zv.y, dz = ev.z - zv.z, dw = ev.w - zv.w;
    float s = fmaf(dx, dx, fmaf(dy, dy, fmaf(dz, dz, dw * dw)));
#pragma unroll
    for (int off = 32; off > 0; off >>= 1) s += __shfl_down(s, off, 64);
    if (lane == 0) { atomicAdd(loss, s); atomicAdd(&counts[code], 1.0f); }
    float* base = nemaw + (size_t)code * DIM + lane * 4;
    atomicAdd(base + 0, OMD * zv.x);
    atomicAdd(base + 1, OMD * zv.y);
    atomicAdd(base + 2, OMD * zv.z);
    atomicAdd(base + 3, OMD * zv.w);
}

// ---------------------------------------------------------------- new_cluster_size, n, loss
__global__ void k_ncs(const float* __restrict__ ema_cs, const float* __restrict__ counts,
                      float* __restrict__ ncs_out, float* __restrict__ ntot,
                      const float* __restrict__ loss_in, float* __restrict__ loss_out) {
    __shared__ float red[16];
    const int t = threadIdx.x;
    float s = 0.0f;
    for (int i = t; i < K_CODES; i += 1024) {
        float v = fmaf(DECAYF, ema_cs[i], OMD * counts[i]);
        ncs_out[i] = v;
        s += v;
    }
#pragma unroll
    for (int off = 32; off > 0; off >>= 1) s += __shfl_down(s, off, 64);
    if ((t & 63) == 0) red[t >> 6] = s;
    __syncthreads();
    if (t < 16) {
        float v = red[t];
#pragma unroll
        for (int off = 8; off > 0; off >>= 1) v += __shfl_down(v, off, 16);
        if (t == 0) {
            *ntot = v;
            *loss_out = 0.25f * (*loss_in) / 8388608.0f;
        }
    }
}

// ---------------------------------------------------------------- new_embedding
__global__ void k_nemb(const float* __restrict__ nemaw, const float* __restrict__ ncs,
                       const float* __restrict__ ntot_p, float* __restrict__ nemb) {
    const int i4 = blockIdx.x * blockDim.x + threadIdx.x;
    const int k  = i4 >> 6;
    const float n   = *ntot_p;
    const float inv = n / (n + (float)K_CODES * EPSF);
    const float cs  = (ncs[k] + EPSF) * inv;
    float4 wv = ((const float4*)nemaw)[i4];
    ((float4*)nemb)[i4] = make_float4(wv.x / cs, wv.y / cs, wv.z / cs, wv.w / cs);
}

extern "C" void kernel_launch(void* const* d_in, const int* in_sizes, int n_in,
                              void* d_out, int out_size, void* d_ws, size_t ws_size,
                              hipStream_t stream) {
    const float* z      = (const float*)d_in[0];
    const float* emb    = (const float*)d_in[1];
    const float* ema_cs = (const float*)d_in[2];
    const float* ema_w  = (const float*)d_in[3];
    float* out = (float*)d_out;

    // workspace layout (bytes):
    //   0         ws_idx    int[32768]
    //   131072    ws_counts float[8192]   (+loss @40960f, +ntot @40961f)
    //   163856    ws_esq    float[8192]
    //   196624    part_v    float[8*32768]
    //   1245200   part_i    int[8*32768]
    //   2293776   zhi       bf16[32768*256]
    //   19070992  zlo       bf16[32768*256]
    //   35848208  ehi       bf16[8192*256]
    //   40042512  elo       bf16[8192*256]   -> total 44236816
    char* wsb = (char*)d_ws;
    int*            ws_idx    = (int*)wsb;
    float*          ws_counts = (float*)(wsb + 131072);
    float*          ws_loss   = ws_counts + K_CODES;
    float*          ws_ntot   = ws_loss + 1;
    float*          ws_esq    = (float*)(wsb + 163856);
    float*          part_v    = (float*)(wsb + 196624);
    int*            part_i    = (int*)(wsb + 1245200);
    unsigned short* zhi       = (unsigned short*)(wsb + 2293776);
    unsigned short* zlo       = (unsigned short*)(wsb + 19070992);
    unsigned short* ehi       = (unsigned short*)(wsb + 35848208);
    unsigned short* elo       = (unsigned short*)(wsb + 40042512);

    const bool mfma_path = (ws_size >= (size_t)44236816);

    if (mfma_path) {
        k_cvt_z      <<<8192, 256, 0, stream>>>(z, zhi, zlo);
        k_cvt_e      <<<2048, 256, 0, stream>>>(emb, ehi, elo, ws_esq, ws_counts);
        k_init_nemaw <<<2048, 256, 0, stream>>>(ema_w, out + O_NEMAW);
        k_argmin_mfma<<<dim3(NROWS / BM_M, NCH), 256, 0, stream>>>(
            zhi, zlo, ehi, elo, ws_esq, part_v, part_i);
        k_reduce_part<<<NROWS / 256, 256, 0, stream>>>(part_v, part_i, ws_idx, out + O_IDX);
    } else {
        k_esq_zero   <<<2048, 256, 0, stream>>>(emb, ws_esq, ws_counts);
        k_init_nemaw <<<2048, 256, 0, stream>>>(ema_w, out + O_NEMAW);
        k_argmin     <<<NROWS / BM, 256, 0, stream>>>(z, emb, ws_esq, ws_idx, out + O_IDX);
    }
    k_gather <<<NROWS / 4, 256, 0, stream>>>(z, emb, ws_idx, out + O_ZQ,
                                             out + O_NEMAW, ws_counts, ws_loss);
    k_ncs    <<<1, 1024, 0, stream>>>(ema_cs, ws_counts, out + O_NCS, ws_ntot,
                                      ws_loss, out + O_LOSS);
    k_nemb   <<<2048, 256, 0, stream>>>(out + O_NEMAW, out + O_NCS, ws_ntot,
                                        out + O_NEMB);
}

// Round 3
// 862.501 us; speedup vs baseline: 3.3286x; 1.4542x over previous
//
#include <hip/hip_runtime.h>
#include <cfloat>

// VQ-VAE vector quantizer. Round 3: unified virtual-K=768 bf16 MFMA argmin,
// occupancy 3 blocks/CU, atomic-free EMA scatter via histogram+buckets.
// N=32768 rows, K=8192 codes, D=256.
#define K_CODES 8192
#define DIM     256
#define NROWS   32768

// d_out float offsets (outputs concatenated in reference return order)
#define O_ZQ    0
#define O_LOSS  8388608
#define O_IDX   8388609
#define O_NEMB  8421377
#define O_NCS   10518529
#define O_NEMAW 10526721

// ---- MFMA path params
#define NCH          4                    // code chunks
#define CODES_PER_CH (K_CODES / NCH)      // 2048
#define NT_TILES     (CODES_PER_CH / 128) // 16

typedef __attribute__((ext_vector_type(8))) short short8;
typedef __attribute__((ext_vector_type(4))) float floatx4;

__device__ __forceinline__ unsigned short f2bf_rne(float x) {
    unsigned u = __float_as_uint(x);
    u += 0x7fffu + ((u >> 16) & 1u);
    return (unsigned short)(u >> 16);
}
__device__ __forceinline__ float bf2f(unsigned short h) {
    return __uint_as_float(((unsigned)h) << 16);
}
__device__ __forceinline__ void async16(const void* g, void* l) {
    __builtin_amdgcn_global_load_lds(
        (const __attribute__((address_space(1))) void*)g,
        (__attribute__((address_space(3))) void*)l, 16, 0, 0);
}

// ---------------------------------------------------------------- z -> zcat [row][512]={bf16(-2z)hi, lo}
__global__ void k_cvt_z(const float* __restrict__ z, unsigned short* __restrict__ zcat) {
    const int i = blockIdx.x * blockDim.x + threadIdx.x;   // float4 idx, 2,097,152
    const int row = i >> 6;
    const int col = (i & 63) << 2;
    float4 v = ((const float4*)z)[i];
    // fold -2 into z: bf16(-2z) == -2*bf16(z) exactly (pow2 scale)
    float nx = -2.0f * v.x, ny = -2.0f * v.y, nz = -2.0f * v.z, nw = -2.0f * v.w;
    ushort4 h, l;
    h.x = f2bf_rne(nx); l.x = f2bf_rne(nx - bf2f(h.x));
    h.y = f2bf_rne(ny); l.y = f2bf_rne(ny - bf2f(h.y));
    h.z = f2bf_rne(nz); l.z = f2bf_rne(nz - bf2f(h.z));
    h.w = f2bf_rne(nw); l.w = f2bf_rne(nw - bf2f(h.w));
    *(ushort4*)&zcat[(size_t)row * 512 + col]       = h;
    *(ushort4*)&zcat[(size_t)row * 512 + 256 + col] = l;
}

// ---------------------------------------------------------------- emb -> ecat [code][512]={hi,lo} + |e|^2 + zero
__global__ void k_cvt_e(const float* __restrict__ emb, unsigned short* __restrict__ ecat,
                        float* __restrict__ esq, int* __restrict__ zero16k) {
    const int gid  = blockIdx.x * blockDim.x + threadIdx.x;  // 524,288
    if (gid < 2 * K_CODES) zero16k[gid] = 0;                 // counts + cursor
    const int code = gid >> 6;
    const int lane = gid & 63;
    const int col  = lane << 2;
    float4 v = ((const float4*)emb)[code * 64 + lane];
    ushort4 h, l;
    h.x = f2bf_rne(v.x); l.x = f2bf_rne(v.x - bf2f(h.x));
    h.y = f2bf_rne(v.y); l.y = f2bf_rne(v.y - bf2f(h.y));
    h.z = f2bf_rne(v.z); l.z = f2bf_rne(v.z - bf2f(h.z));
    h.w = f2bf_rne(v.w); l.w = f2bf_rne(v.w - bf2f(h.w));
    *(ushort4*)&ecat[(size_t)code * 512 + col]       = h;
    *(ushort4*)&ecat[(size_t)code * 512 + 256 + col] = l;
    float s = fmaf(v.x, v.x, fmaf(v.y, v.y, fmaf(v.z, v.z, v.w * v.w)));
#pragma unroll
    for (int off = 32; off > 0; off >>= 1) s += __shfl_down(s, off, 64);
    if (lane == 0) esq[code] = s;
}

// ---------------------------------------------------------------- MFMA argmin GEMM (virtual K=768)
// score(n,k) = esq[k] + dot(zcat_n, ecat_k segs) where zcat encodes -2z.
// A order {hi,hi,lo}: off_a=(k0&255)|((k0&512)>>1); B order {hi,lo,hi}: off_b=k0&511.
// Block 256 = 4 waves; wave w: rows (w>>1)*64, cols (w&1)*64; acc 4x4 of 16x16x32 init'd with esq.
__global__ __launch_bounds__(256, 3) void k_argmin_mfma(
        const unsigned short* __restrict__ zcat, const unsigned short* __restrict__ ecat,
        const float* __restrict__ esq,
        float* __restrict__ part_v, int* __restrict__ part_i) {
    __shared__ __align__(16) unsigned short a_s[128 * 32];  // 8 KB
    __shared__ __align__(16) unsigned short b_s[128 * 32];  // 8 KB
    const int t    = threadIdx.x;
    const int w    = t >> 6;
    const int lane = t & 63;
    const int quad = lane >> 4;
    const int m    = lane & 15;
    const int wrow = (w >> 1) * 64;
    const int wcol = (w & 1) * 64;
    const int row0   = blockIdx.x * 128;
    const int cbase0 = blockIdx.y * CODES_PER_CH;
    const int srow = lane >> 2;            // staging: lane covers row srow of 16-row chunk
    const int sk   = (lane & 3) * 8;       // 8 bf16 = 16 B per lane

    const size_t aBase = (size_t)(row0 + srow) * 512 + sk;
    const size_t bBase = (size_t)(cbase0 + srow) * 512 + sk;

    float    best_v[16];
    unsigned best_p[4];
#pragma unroll
    for (int r = 0; r < 16; ++r) best_v[r] = FLT_MAX;
#pragma unroll
    for (int i = 0; i < 4; ++i) best_p[i] = 0u;

    for (int nt = 0; nt < NT_TILES; ++nt) {
        const int cb = cbase0 + nt * 128;
        float esqv[4];
#pragma unroll
        for (int j = 0; j < 4; ++j) esqv[j] = esq[cb + wcol + j * 16 + m];
        floatx4 acc[4][4];
#pragma unroll
        for (int i = 0; i < 4; ++i)
#pragma unroll
            for (int j = 0; j < 4; ++j)
                acc[i][j] = (floatx4){esqv[j], esqv[j], esqv[j], esqv[j]};

        for (int k0 = 0; k0 < 768; k0 += 32) {
            const int off_a = (k0 & 255) | ((k0 & 512) >> 1);
            const int off_b = k0 & 511;
            __syncthreads();   // prior iter's ds_reads done before overwrite
            if (w < 2) {       // waves 0,1 stage A (128x32 bf16)
#pragma unroll
                for (int c = 0; c < 4; ++c) {
                    const int q = w * 4 + c;
                    async16(zcat + aBase + (size_t)q * (16 * 512) + off_a, &a_s[q * 512]);
                }
            } else {           // waves 2,3 stage B
#pragma unroll
                for (int c = 0; c < 4; ++c) {
                    const int q = (w - 2) * 4 + c;
                    async16(ecat + bBase + (size_t)(nt * 128 + q * 16) * 512 + off_b,
                            &b_s[q * 512]);
                }
            }
            __syncthreads();   // barrier drains vmcnt(0): staged data visible
            short8 af[4], bfr[4];
#pragma unroll
            for (int i = 0; i < 4; ++i)
                af[i] = *(const short8*)&a_s[(wrow + i * 16 + m) * 32 + quad * 8];
#pragma unroll
            for (int j = 0; j < 4; ++j)
                bfr[j] = *(const short8*)&b_s[(wcol + j * 16 + m) * 32 + quad * 8];
#pragma unroll
            for (int i = 0; i < 4; ++i)
#pragma unroll
                for (int j = 0; j < 4; ++j)
                    acc[i][j] = __builtin_amdgcn_mfma_f32_16x16x32_bf16(
                        af[i], bfr[j], acc[i][j], 0, 0, 0);
        }
        // epilogue: acc value IS the score. codes ascend in (nt,j): strict < = first-min.
#pragma unroll
        for (int j = 0; j < 4; ++j) {
            const unsigned cand = (unsigned)(nt * 4 + j);   // 6 bits
#pragma unroll
            for (int i = 0; i < 4; ++i)
#pragma unroll
                for (int reg = 0; reg < 4; ++reg) {
                    const float s = acc[i][j][reg];
                    const int r = i * 4 + reg;
                    if (s < best_v[r]) {
                        best_v[r] = s;
                        best_p[i] = (best_p[i] & ~(255u << (reg * 8))) | (cand << (reg * 8));
                    }
                }
        }
    }
    // reconstruct codes, butterfly across the 16 lanes sharing each row
    __syncthreads();               // staging LDS free for reuse
    float* redv = (float*)a_s;     // [128][2]
    int*   redi = (int*)b_s;       // [128][2]
#pragma unroll
    for (int i = 0; i < 4; ++i)
#pragma unroll
        for (int reg = 0; reg < 4; ++reg) {
            const int r = i * 4 + reg;
            const unsigned b = (best_p[i] >> (reg * 8)) & 63u;
            float v  = best_v[r];
            int   bi = cbase0 + (int)(b >> 2) * 128 + wcol + (int)(b & 3) * 16 + m;
#pragma unroll
            for (int off = 1; off < 16; off <<= 1) {
                const float ov = __shfl_xor(v, off, 64);
                const int   oi = __shfl_xor(bi, off, 64);
                if (ov < v || (ov == v && oi < bi)) { v = ov; bi = oi; }
            }
            if (m == 0) {
                const int row = wrow + i * 16 + quad * 4 + reg;
                redv[row * 2 + (w & 1)] = v;
                redi[row * 2 + (w & 1)] = bi;
            }
        }
    __syncthreads();
    if (t < 128) {
        const float v0 = redv[t * 2], v1 = redv[t * 2 + 1];
        const int   i0 = redi[t * 2], i1 = redi[t * 2 + 1];
        const bool  b1 = (v1 < v0) || (v1 == v0 && i1 < i0);
        const size_t o = (size_t)blockIdx.y * NROWS + row0 + t;
        part_v[o] = b1 ? v1 : v0;
        part_i[o] = b1 ? i1 : i0;
    }
}

// ---------------------------------------------------------------- merge partials + histogram
__global__ void k_reduce_part(const float* __restrict__ pv, const int* __restrict__ pi,
                              int* __restrict__ idx_i, float* __restrict__ idx_f,
                              int* __restrict__ counts) {
    const int r = blockIdx.x * blockDim.x + threadIdx.x;
    float v = pv[r]; int bi = pi[r];
#pragma unroll
    for (int c = 1; c < NCH; ++c) {
        const float v2 = pv[(size_t)c * NROWS + r];
        const int   i2 = pi[(size_t)c * NROWS + r];
        if (v2 < v || (v2 == v && i2 < bi)) { v = v2; bi = i2; }
    }
    idx_i[r] = bi;
    idx_f[r] = (float)bi;
    atomicAdd(&counts[bi], 1);
}

// ---------------------------------------------------------------- exclusive scan of counts[8192]
__global__ void k_scan(const int* __restrict__ counts, int* __restrict__ offsets) {
    __shared__ int wsum[16];
    const int t = threadIdx.x;          // 1024
    const int lane = t & 63, w = t >> 6;
    int c[8]; int s = 0;
#pragma unroll
    for (int u = 0; u < 8; ++u) { c[u] = counts[t * 8 + u]; s += c[u]; }
    int inc = s;
#pragma unroll
    for (int off = 1; off < 64; off <<= 1) {
        const int n = __shfl_up(inc, off, 64);
        if (lane >= off) inc += n;
    }
    if (lane == 63) wsum[w] = inc;
    __syncthreads();
    if (t < 16) {
        int v = wsum[t];
#pragma unroll
        for (int off = 1; off < 16; off <<= 1) {
            const int n = __shfl_up(v, off, 64);
            if (t >= off) v += n;
        }
        wsum[t] = v;
    }
    __syncthreads();
    int base = (w > 0 ? wsum[w - 1] : 0) + (inc - s);
#pragma unroll
    for (int u = 0; u < 8; ++u) { offsets[t * 8 + u] = base; base += c[u]; }
}

// ---------------------------------------------------------------- zq + loss partials + bucket scatter
// one wave per row (4 rows/block)
__global__ void k_zq(const float* __restrict__ z, const float* __restrict__ emb,
                     const int* __restrict__ idx_i, const int* __restrict__ offsets,
                     int* __restrict__ cursor, int* __restrict__ buckets,
                     float* __restrict__ zq, float* __restrict__ losspart) {
    __shared__ float lred[4];
    const int t = threadIdx.x;
    const int wr = t >> 6, lane = t & 63;
    const int row = blockIdx.x * 4 + wr;
    const int code = idx_i[row];
    float4 zv = ((const float4*)z)[row * 64 + lane];
    float4 ev = ((const float4*)emb)[(size_t)code * 64 + lane];
    float4 o = make_float4(zv.x + (ev.x - zv.x), zv.y + (ev.y - zv.y),
                           zv.z + (ev.z - zv.z), zv.w + (ev.w - zv.w));
    ((float4*)zq)[row * 64 + lane] = o;
    float dx = ev.x - zv.x, dy = ev.y - zv.y, dz = ev.z - zv.z, dw = ev.w - zv.w;
    float s = fmaf(dx, dx, fmaf(dy, dy, fmaf(dz, dz, dw * dw)));
#pragma unroll
    for (int off = 32; off > 0; off >>= 1) s += __shfl_down(s, off, 64);
    if (lane == 0) {
        lred[wr] = s;
        const int pos = atomicAdd(&cursor[code], 1);
        buckets[offsets[code] + pos] = row;
    }
    __syncthreads();
    if (t == 0) losspart[blockIdx.x] = (lred[0] + lred[1]) + (lred[2] + lred[3]);
}

// ---------------------------------------------------------------- dw + new_ema_w (one block per code)
__global__ void k_dw(const float* __restrict__ z, const float* __restrict__ ema_w,
                     const int* __restrict__ counts, const int* __restrict__ offsets,
                     const int* __restrict__ buckets, float* __restrict__ nemaw) {
    const int code = blockIdx.x;
    const int d    = threadIdx.x;         // 256 = DIM
    const int cnt  = counts[code];
    const int off  = offsets[code];
    float acc = 0.0f;
    for (int it = 0; it < cnt; ++it)
        acc += z[(size_t)buckets[off + it] * DIM + d];
    nemaw[(size_t)code * DIM + d] =
        fmaf(0.99f, ema_w[(size_t)code * DIM + d], 0.01f * acc);
}

// ---------------------------------------------------------------- new_cluster_size + n + loss
__global__ void k_ncs(const float* __restrict__ ema_cs, const int* __restrict__ counts,
                      const float* __restrict__ losspart,
                      float* __restrict__ ncs_out, float* __restrict__ ntot,
                      float* __restrict__ loss_out) {
    __shared__ float red1[16], red2[16];
    const int t = threadIdx.x;            // 1024
    float s1 = 0.0f, s2 = 0.0f;
    for (int i = t; i < K_CODES; i += 1024) {
        const float v = fmaf(0.99f, ema_cs[i], 0.01f * (float)counts[i]);
        ncs_out[i] = v;
        s1 += v;
        s2 += losspart[i];
    }
#pragma unroll
    for (int off = 32; off > 0; off >>= 1) {
        s1 += __shfl_down(s1, off, 64);
        s2 += __shfl_down(s2, off, 64);
    }
    if ((t & 63) == 0) { red1[t >> 6] = s1; red2[t >> 6] = s2; }
    __syncthreads();
    if (t < 16) {
        float v1 = red1[t], v2 = red2[t];
#pragma unroll
        for (int off = 8; off > 0; off >>= 1) {
            v1 += __shfl_down(v1, off, 16);
            v2 += __shfl_down(v2, off, 16);
        }
        if (t == 0) {
            *ntot = v1;
            *loss_out = 0.25f * v2 / 8388608.0f;
        }
    }
}

// ---------------------------------------------------------------- new_embedding
__global__ void k_nemb(const float* __restrict__ nemaw, const float* __restrict__ ncs,
                       const float* __restrict__ ntot_p, float* __restrict__ nemb) {
    const int i4 = blockIdx.x * blockDim.x + threadIdx.x;  // float4 idx, 524288
    const int k  = i4 >> 6;
    const float n   = *ntot_p;
    const float inv = n / (n + (float)K_CODES * 1e-5f);
    const float cs  = (ncs[k] + 1e-5f) * inv;
    float4 wv = ((const float4*)nemaw)[i4];
    ((float4*)nemb)[i4] = make_float4(wv.x / cs, wv.y / cs, wv.z / cs, wv.w / cs);
}

// ================================================================ fp32 fallback path (round-1 verified)
#define BM   64
#define BN   128
#define LSTR 36

__global__ void k_esq_zero_fb(const float* __restrict__ emb, float* __restrict__ esq,
                              float* __restrict__ zbuf) {
    const int gid  = blockIdx.x * blockDim.x + threadIdx.x;
    if (gid < K_CODES + 2) zbuf[gid] = 0.0f;
    const int code = gid >> 6;
    const int lane = gid & 63;
    float4 v = ((const float4*)emb)[code * 64 + lane];
    float s = fmaf(v.x, v.x, fmaf(v.y, v.y, fmaf(v.z, v.z, v.w * v.w)));
#pragma unroll
    for (int off = 32; off > 0; off >>= 1) s += __shfl_down(s, off, 64);
    if (lane == 0) esq[code] = s;
}

__global__ void k_init_nemaw_fb(const float* __restrict__ ema_w, float* __restrict__ out) {
    const int i = blockIdx.x * blockDim.x + threadIdx.x;
    float4 v = ((const float4*)ema_w)[i];
    ((float4*)out)[i] = make_float4(0.99f * v.x, 0.99f * v.y, 0.99f * v.z, 0.99f * v.w);
}

__global__ __launch_bounds__(256, 2) void k_argmin_fb(
        const float* __restrict__ z, const float* __restrict__ emb,
        const float* __restrict__ esq, int* __restrict__ idx_i, float* __restrict__ idx_f) {
    __shared__ float z_s[BM * LSTR];
    __shared__ float e_s[BN * LSTR];
    const int t = threadIdx.x, tx = t & 15, ty = t >> 4;
    const int row0 = blockIdx.x * BM;
    float best[4]; int bidx[4];
#pragma unroll
    for (int r = 0; r < 4; ++r) { best[r] = FLT_MAX; bidx[r] = 0; }
    for (int k0 = 0; k0 < K_CODES; k0 += BN) {
        float acc[4][8];
#pragma unroll
        for (int r = 0; r < 4; ++r)
#pragma unroll
            for (int c = 0; c < 8; ++c) acc[r][c] = 0.0f;
        for (int d0 = 0; d0 < DIM; d0 += 32) {
            __syncthreads();
#pragma unroll
            for (int i = 0; i < 2; ++i) {
                int f = i * 256 + t, r = f >> 3, c4 = (f & 7) << 2;
                *(float4*)&z_s[r * LSTR + c4] =
                    *(const float4*)(z + (size_t)(row0 + r) * DIM + d0 + c4);
            }
#pragma unroll
            for (int i = 0; i < 4; ++i) {
                int f = i * 256 + t, c = f >> 3, c4 = (f & 7) << 2;
                *(float4*)&e_s[c * LSTR + c4] =
                    *(const float4*)(emb + (size_t)(k0 + c) * DIM + d0 + c4);
            }
            __syncthreads();
#pragma unroll
            for (int dd = 0; dd < 32; dd += 4) {
                float4 a[4], b[8];
#pragma unroll
                for (int j = 0; j < 4; ++j)
                    a[j] = *(const float4*)&z_s[(ty * 4 + j) * LSTR + dd];
#pragma unroll
                for (int j = 0; j < 8; ++j)
                    b[j] = *(const float4*)&e_s[(tx + 16 * j) * LSTR + dd];
#pragma unroll
                for (int r = 0; r < 4; ++r)
#pragma unroll
                    for (int c = 0; c < 8; ++c) {
                        acc[r][c] = fmaf(a[r].x, b[c].x, acc[r][c]);
                        acc[r][c] = fmaf(a[r].y, b[c].y, acc[r][c]);
                        acc[r][c] = fmaf(a[r].z, b[c].z, acc[r][c]);
                        acc[r][c] = fmaf(a[r].w, b[c].w, acc[r][c]);
                    }
            }
        }
#pragma unroll
        for (int c = 0; c < 8; ++c) {
            const int code = k0 + tx + 16 * c;
            const float es = esq[code];
#pragma unroll
            for (int r = 0; r < 4; ++r) {
                float s = fmaf(-2.0f, acc[r][c], es);
                if (s < best[r] || (s == best[r] && code < bidx[r])) {
                    best[r] = s; bidx[r] = code;
                }
            }
        }
    }
    __syncthreads();
    float* rv = e_s; int* ri = (int*)z_s;
#pragma unroll
    for (int r = 0; r < 4; ++r) {
        rv[(ty * 4 + r) * 16 + tx] = best[r];
        ri[(ty * 4 + r) * 16 + tx] = bidx[r];
    }
    __syncthreads();
    if (t < 64) {
        float mv = rv[t * 16]; int mi = ri[t * 16];
#pragma unroll
        for (int i = 1; i < 16; ++i) {
            float v = rv[t * 16 + i]; int vi = ri[t * 16 + i];
            if (v < mv || (v == mv && vi < mi)) { mv = v; mi = vi; }
        }
        idx_i[row0 + t] = mi;
        idx_f[row0 + t] = (float)mi;
    }
}

__global__ void k_gather_fb(const float* __restrict__ z, const float* __restrict__ emb,
                            const int* __restrict__ idx_i, float* __restrict__ zq,
                            float* __restrict__ nemaw, float* __restrict__ counts,
                            float* __restrict__ loss) {
    const int gid  = blockIdx.x * blockDim.x + threadIdx.x;
    const int row  = gid >> 6;
    const int lane = gid & 63;
    const int code = idx_i[row];
    float4 zv = ((const float4*)z)[row * 64 + lane];
    float4 ev = ((const float4*)emb)[(size_t)code * 64 + lane];
    float4 o = make_float4(zv.x + (ev.x - zv.x), zv.y + (ev.y - zv.y),
                           zv.z + (ev.z - zv.z), zv.w + (ev.w - zv.w));
    ((float4*)zq)[row * 64 + lane] = o;
    float dx = ev.x - zv.x, dy = ev.y - zv.y, dz = ev.z - zv.z, dw = ev.w - zv.w;
    float s = fmaf(dx, dx, fmaf(dy, dy, fmaf(dz, dz, dw * dw)));
#pragma unroll
    for (int off = 32; off > 0; off >>= 1) s += __shfl_down(s, off, 64);
    if (lane == 0) { atomicAdd(loss, s); atomicAdd(&counts[code], 1.0f); }
    float* base = nemaw + (size_t)code * DIM + lane * 4;
    atomicAdd(base + 0, 0.01f * zv.x);
    atomicAdd(base + 1, 0.01f * zv.y);
    atomicAdd(base + 2, 0.01f * zv.z);
    atomicAdd(base + 3, 0.01f * zv.w);
}

__global__ void k_ncs_fb(const float* __restrict__ ema_cs, const float* __restrict__ counts,
                         float* __restrict__ ncs_out, float* __restrict__ ntot,
                         const float* __restrict__ loss_in, float* __restrict__ loss_out) {
    __shared__ float red[16];
    const int t = threadIdx.x;
    float s = 0.0f;
    for (int i = t; i < K_CODES; i += 1024) {
        float v = fmaf(0.99f, ema_cs[i], 0.01f * counts[i]);
        ncs_out[i] = v; s += v;
    }
#pragma unroll
    for (int off = 32; off > 0; off >>= 1) s += __shfl_down(s, off, 64);
    if ((t & 63) == 0) red[t >> 6] = s;
    __syncthreads();
    if (t < 16) {
        float v = red[t];
#pragma unroll
        for (int off = 8; off > 0; off >>= 1) v += __shfl_down(v, off, 16);
        if (t == 0) { *ntot = v; *loss_out = 0.25f * (*loss_in) / 8388608.0f; }
    }
}

extern "C" void kernel_launch(void* const* d_in, const int* in_sizes, int n_in,
                              void* d_out, int out_size, void* d_ws, size_t ws_size,
                              hipStream_t stream) {
    const float* z      = (const float*)d_in[0];
    const float* emb    = (const float*)d_in[1];
    const float* ema_cs = (const float*)d_in[2];
    const float* ema_w  = (const float*)d_in[3];
    float* out = (float*)d_out;
    char* wsb = (char*)d_ws;

    // ---- MFMA-path workspace layout (bytes), total 43,417,616
    unsigned short* zcat    = (unsigned short*)wsb;                  // 33,554,432
    unsigned short* ecat    = (unsigned short*)(wsb + 33554432);     //  8,388,608
    float*          part_v  = (float*)(wsb + 41943040);              //    524,288
    int*            part_i  = (int*)  (wsb + 42467328);              //    524,288
    float*          esq     = (float*)(wsb + 42991616);              //     32,768
    int*            ws_idx  = (int*)  (wsb + 43024384);              //    131,072
    int*            counts  = (int*)  (wsb + 43155456);              //     32,768
    int*            cursor  = (int*)  (wsb + 43188224);              //     32,768 (contiguous w/ counts)
    int*            offsets = (int*)  (wsb + 43220992);              //     32,768
    int*            buckets = (int*)  (wsb + 43253760);              //    131,072
    float*          lpart   = (float*)(wsb + 43384832);              //     32,768
    float*          ws_loss = (float*)(wsb + 43417600);
    float*          ws_ntot = ws_loss + 1;

    if (ws_size >= (size_t)43417616) {
        k_cvt_z      <<<8192, 256, 0, stream>>>(z, zcat);
        k_cvt_e      <<<2048, 256, 0, stream>>>(emb, ecat, esq, counts);
        k_argmin_mfma<<<dim3(NROWS / 128, NCH), 256, 0, stream>>>(
            zcat, ecat, esq, part_v, part_i);
        k_reduce_part<<<NROWS / 256, 256, 0, stream>>>(part_v, part_i, ws_idx,
                                                       out + O_IDX, counts);
        k_scan       <<<1, 1024, 0, stream>>>(counts, offsets);
        k_zq         <<<NROWS / 4, 256, 0, stream>>>(z, emb, ws_idx, offsets, cursor,
                                                     buckets, out + O_ZQ, lpart);
        k_dw         <<<K_CODES, 256, 0, stream>>>(z, ema_w, counts, offsets, buckets,
                                                   out + O_NEMAW);
        k_ncs        <<<1, 1024, 0, stream>>>(ema_cs, counts, lpart, out + O_NCS,
                                              ws_ntot, out + O_LOSS);
        k_nemb       <<<2048, 256, 0, stream>>>(out + O_NEMAW, out + O_NCS, ws_ntot,
                                                out + O_NEMB);
    } else {
        // small-ws fallback (round-1 verified fp32 path)
        int*   f_idx    = (int*)wsb;
        float* f_counts = (float*)(wsb + 131072);
        float* f_loss   = f_counts + K_CODES;
        float* f_ntot   = f_loss + 1;
        float* f_esq    = (float*)(wsb + 163856);
        k_esq_zero_fb  <<<2048, 256, 0, stream>>>(emb, f_esq, f_counts);
        k_init_nemaw_fb<<<2048, 256, 0, stream>>>(ema_w, out + O_NEMAW);
        k_argmin_fb    <<<NROWS / BM, 256, 0, stream>>>(z, emb, f_esq, f_idx, out + O_IDX);
        k_gather_fb    <<<NROWS / 4, 256, 0, stream>>>(z, emb, f_idx, out + O_ZQ,
                                                       out + O_NEMAW, f_counts, f_loss);
        k_ncs_fb       <<<1, 1024, 0, stream>>>(ema_cs, f_counts, out + O_NCS, f_ntot,
                                                f_loss, out + O_LOSS);
        k_nemb         <<<2048, 256, 0, stream>>>(out + O_NEMAW, out + O_NCS, f_ntot,
                                                  out + O_NEMB);
    }
}

// Round 4
// 765.492 us; speedup vs baseline: 3.7504x; 1.1267x over previous
//
#include <hip/hip_runtime.h>
#include <cfloat>

// VQ-VAE vector quantizer. Round 4: BK=64 (half the barriers) + XOR-swizzled
// LDS staging (kills the 8-way bank conflicts) + fused side kernels.
// N=32768 rows, K=8192 codes, D=256.
#define K_CODES 8192
#define DIM     256
#define NROWS   32768

// d_out float offsets (outputs concatenated in reference return order)
#define O_ZQ    0
#define O_LOSS  8388608
#define O_IDX   8388609
#define O_NEMB  8421377
#define O_NCS   10518529
#define O_NEMAW 10526721

// ---- MFMA path params
#define NCH          4                    // code chunks
#define CODES_PER_CH (K_CODES / NCH)      // 2048
#define NT_TILES     (CODES_PER_CH / 128) // 16

typedef __attribute__((ext_vector_type(8))) short short8;
typedef __attribute__((ext_vector_type(4))) float floatx4;

__device__ __forceinline__ unsigned short f2bf_rne(float x) {
    unsigned u = __float_as_uint(x);
    u += 0x7fffu + ((u >> 16) & 1u);
    return (unsigned short)(u >> 16);
}
__device__ __forceinline__ float bf2f(unsigned short h) {
    return __uint_as_float(((unsigned)h) << 16);
}
__device__ __forceinline__ void async16(const void* g, void* l) {
    __builtin_amdgcn_global_load_lds(
        (const __attribute__((address_space(1))) void*)g,
        (__attribute__((address_space(3))) void*)l, 16, 0, 0);
}

// ---------------------------------------------------------------- fused convert: z & emb -> {hi,lo} bf16 + |e|^2 + zero
// blocks [0,8192): z part (float4 idx). blocks [8192,10240): emb part + zeroing.
__global__ void k_prep(const float* __restrict__ z, const float* __restrict__ emb,
                       unsigned short* __restrict__ zcat, unsigned short* __restrict__ ecat,
                       float* __restrict__ esq, int* __restrict__ zero16k) {
    const int b = blockIdx.x;
    if (b < 8192) {
        const int i = b * 256 + threadIdx.x;         // float4 idx, 2,097,152
        const int row = i >> 6;
        const int col = (i & 63) << 2;
        float4 v = ((const float4*)z)[i];
        // fold -2 into z: bf16(-2z) == -2*bf16(z) exactly (pow2 scale)
        float nx = -2.0f * v.x, ny = -2.0f * v.y, nz = -2.0f * v.z, nw = -2.0f * v.w;
        ushort4 h, l;
        h.x = f2bf_rne(nx); l.x = f2bf_rne(nx - bf2f(h.x));
        h.y = f2bf_rne(ny); l.y = f2bf_rne(ny - bf2f(h.y));
        h.z = f2bf_rne(nz); l.z = f2bf_rne(nz - bf2f(h.z));
        h.w = f2bf_rne(nw); l.w = f2bf_rne(nw - bf2f(h.w));
        *(ushort4*)&zcat[(size_t)row * 512 + col]       = h;
        *(ushort4*)&zcat[(size_t)row * 512 + 256 + col] = l;
    } else {
        const int gid  = (b - 8192) * 256 + threadIdx.x;  // 0..524287
        if (gid < 2 * K_CODES) zero16k[gid] = 0;          // counts + cursor
        const int code = gid >> 6;
        const int lane = gid & 63;
        const int col  = lane << 2;
        float4 v = ((const float4*)emb)[code * 64 + lane];
        ushort4 h, l;
        h.x = f2bf_rne(v.x); l.x = f2bf_rne(v.x - bf2f(h.x));
        h.y = f2bf_rne(v.y); l.y = f2bf_rne(v.y - bf2f(h.y));
        h.z = f2bf_rne(v.z); l.z = f2bf_rne(v.z - bf2f(h.z));
        h.w = f2bf_rne(v.w); l.w = f2bf_rne(v.w - bf2f(h.w));
        *(ushort4*)&ecat[(size_t)code * 512 + col]       = h;
        *(ushort4*)&ecat[(size_t)code * 512 + 256 + col] = l;
        float s = fmaf(v.x, v.x, fmaf(v.y, v.y, fmaf(v.z, v.z, v.w * v.w)));
#pragma unroll
        for (int off = 32; off > 0; off >>= 1) s += __shfl_down(s, off, 64);
        if (lane == 0) esq[code] = s;
    }
}

// ---------------------------------------------------------------- MFMA argmin GEMM (virtual K=768, BK=64)
// score(n,k) = esq[k] + dot(zcat_n, ecat_k segs), zcat encodes -2z.
// A segs {hi,hi,lo}: off_a=(k0&255)|((k0&512)>>1); B segs {hi,lo,hi}: off_b=k0&511.
// LDS layout XOR-swizzled: logical (row R, 16B-chunk C) lives at ushort
// R*64 + ((C ^ (R&7))*8). Staging picks the permuted global source per lane so
// global_load_lds's fixed lane->LDS map lands each 16B where the swizzle wants it.
// Fragment b128 reads then hit all 8 bank-quads 2x each -> conflict-free.
__global__ __launch_bounds__(256, 3) void k_argmin_mfma(
        const unsigned short* __restrict__ zcat, const unsigned short* __restrict__ ecat,
        const float* __restrict__ esq,
        float* __restrict__ part_v, int* __restrict__ part_i) {
    __shared__ __align__(16) unsigned short a_s[128 * 64];  // 16 KB
    __shared__ __align__(16) unsigned short b_s[128 * 64];  // 16 KB
    const int t    = threadIdx.x;
    const int w    = t >> 6;
    const int lane = t & 63;
    const int quad = lane >> 4;
    const int m    = lane & 15;
    const int wrow = (w >> 1) * 64;
    const int wcol = (w & 1) * 64;
    const int row0   = blockIdx.x * 128;
    const int cbase0 = blockIdx.y * CODES_PER_CH;
    // staging geometry: wave chunk = 8 rows x 128B; lane covers 16B
    const int r8   = lane >> 3;                 // row within chunk
    const int cswz = ((lane & 7) ^ r8) * 8;     // swizzled bf16 col offset
    const size_t aBase = (size_t)(row0 + r8) * 512 + cswz;
    const size_t bBase = (size_t)(cbase0 + r8) * 512 + cswz;
    // fragment-read swizzle offsets (ushort): half h chunk index = h*4+quad
    const int mx  = m & 7;
    const int xo0 = ((0 + quad) ^ mx) * 8;
    const int xo1 = ((4 + quad) ^ mx) * 8;

    float    best_v[16];
    unsigned best_p[4];
#pragma unroll
    for (int r = 0; r < 16; ++r) best_v[r] = FLT_MAX;
#pragma unroll
    for (int i = 0; i < 4; ++i) best_p[i] = 0u;

    for (int nt = 0; nt < NT_TILES; ++nt) {
        const int cb = cbase0 + nt * 128;
        float esqv[4];
#pragma unroll
        for (int j = 0; j < 4; ++j) esqv[j] = esq[cb + wcol + j * 16 + m];
        floatx4 acc[4][4];
#pragma unroll
        for (int i = 0; i < 4; ++i)
#pragma unroll
            for (int j = 0; j < 4; ++j)
                acc[i][j] = (floatx4){esqv[j], esqv[j], esqv[j], esqv[j]};

        for (int k0 = 0; k0 < 768; k0 += 64) {
            const int off_a = (k0 & 255) | ((k0 & 512) >> 1);
            const int off_b = k0 & 511;
            __syncthreads();   // prior iter's ds_reads done before overwrite
            if (w < 2) {       // waves 0,1 stage A: 128 rows x 64 k = 16 chunks
#pragma unroll
                for (int c = 0; c < 8; ++c) {
                    const int q = w * 8 + c;
                    async16(zcat + aBase + (size_t)q * (8 * 512) + off_a, &a_s[q * 512]);
                }
            } else {           // waves 2,3 stage B
#pragma unroll
                for (int c = 0; c < 8; ++c) {
                    const int q = (w - 2) * 8 + c;
                    async16(ecat + bBase + (size_t)(nt * 128 + q * 8) * 512 + off_b,
                            &b_s[q * 512]);
                }
            }
            __syncthreads();   // barrier drains vmcnt(0): staged data visible
            {   // k sub-step 0: virtual k [k0, k0+32)
                short8 af[4], bfr[4];
#pragma unroll
                for (int i = 0; i < 4; ++i)
                    af[i] = *(const short8*)&a_s[(wrow + i * 16 + m) * 64 + xo0];
#pragma unroll
                for (int j = 0; j < 4; ++j)
                    bfr[j] = *(const short8*)&b_s[(wcol + j * 16 + m) * 64 + xo0];
#pragma unroll
                for (int i = 0; i < 4; ++i)
#pragma unroll
                    for (int j = 0; j < 4; ++j)
                        acc[i][j] = __builtin_amdgcn_mfma_f32_16x16x32_bf16(
                            af[i], bfr[j], acc[i][j], 0, 0, 0);
            }
            {   // k sub-step 1: virtual k [k0+32, k0+64)
                short8 af[4], bfr[4];
#pragma unroll
                for (int i = 0; i < 4; ++i)
                    af[i] = *(const short8*)&a_s[(wrow + i * 16 + m) * 64 + xo1];
#pragma unroll
                for (int j = 0; j < 4; ++j)
                    bfr[j] = *(const short8*)&b_s[(wcol + j * 16 + m) * 64 + xo1];
#pragma unroll
                for (int i = 0; i < 4; ++i)
#pragma unroll
                    for (int j = 0; j < 4; ++j)
                        acc[i][j] = __builtin_amdgcn_mfma_f32_16x16x32_bf16(
                            af[i], bfr[j], acc[i][j], 0, 0, 0);
            }
        }
        // epilogue: acc IS the score. codes ascend in (nt,j): strict < = first-min.
#pragma unroll
        for (int j = 0; j < 4; ++j) {
            const unsigned cand = (unsigned)(nt * 4 + j);   // 6 bits
#pragma unroll
            for (int i = 0; i < 4; ++i)
#pragma unroll
                for (int reg = 0; reg < 4; ++reg) {
                    const float s = acc[i][j][reg];
                    const int r = i * 4 + reg;
                    if (s < best_v[r]) {
                        best_v[r] = s;
                        best_p[i] = (best_p[i] & ~(255u << (reg * 8))) | (cand << (reg * 8));
                    }
                }
        }
    }
    // reconstruct codes, butterfly across the 16 lanes sharing each row
    __syncthreads();               // staging LDS free for reuse
    float* redv = (float*)a_s;     // [128][2]
    int*   redi = (int*)b_s;       // [128][2]
#pragma unroll
    for (int i = 0; i < 4; ++i)
#pragma unroll
        for (int reg = 0; reg < 4; ++reg) {
            const int r = i * 4 + reg;
            const unsigned b = (best_p[i] >> (reg * 8)) & 63u;
            float v  = best_v[r];
            int   bi = cbase0 + (int)(b >> 2) * 128 + wcol + (int)(b & 3) * 16 + m;
#pragma unroll
            for (int off = 1; off < 16; off <<= 1) {
                const float ov = __shfl_xor(v, off, 64);
                const int   oi = __shfl_xor(bi, off, 64);
                if (ov < v || (ov == v && oi < bi)) { v = ov; bi = oi; }
            }
            if (m == 0) {
                const int row = wrow + i * 16 + quad * 4 + reg;
                redv[row * 2 + (w & 1)] = v;
                redi[row * 2 + (w & 1)] = bi;
            }
        }
    __syncthreads();
    if (t < 128) {
        const float v0 = redv[t * 2], v1 = redv[t * 2 + 1];
        const int   i0 = redi[t * 2], i1 = redi[t * 2 + 1];
        const bool  b1 = (v1 < v0) || (v1 == v0 && i1 < i0);
        const size_t o = (size_t)blockIdx.y * NROWS + row0 + t;
        part_v[o] = b1 ? v1 : v0;
        part_i[o] = b1 ? i1 : i0;
    }
}

// ---------------------------------------------------------------- merge partials + histogram
__global__ void k_reduce_part(const float* __restrict__ pv, const int* __restrict__ pi,
                              int* __restrict__ idx_i, float* __restrict__ idx_f,
                              int* __restrict__ counts) {
    const int r = blockIdx.x * blockDim.x + threadIdx.x;
    float v = pv[r]; int bi = pi[r];
#pragma unroll
    for (int c = 1; c < NCH; ++c) {
        const float v2 = pv[(size_t)c * NROWS + r];
        const int   i2 = pi[(size_t)c * NROWS + r];
        if (v2 < v || (v2 == v && i2 < bi)) { v = v2; bi = i2; }
    }
    idx_i[r] = bi;
    idx_f[r] = (float)bi;
    atomicAdd(&counts[bi], 1);
}

// ---------------------------------------------------------------- scan + new_cluster_size + n  (1 block, 1024 thr)
__global__ void k_scan_ncs(const int* __restrict__ counts, const float* __restrict__ ema_cs,
                           int* __restrict__ offsets, float* __restrict__ ncs_out,
                           float* __restrict__ ntot) {
    __shared__ int   wsum[16];
    __shared__ float red[16];
    const int t = threadIdx.x;
    const int lane = t & 63, w = t >> 6;
    int c[8]; int s = 0; float fs = 0.0f;
#pragma unroll
    for (int u = 0; u < 8; ++u) {
        c[u] = counts[t * 8 + u]; s += c[u];
        const float v = fmaf(0.99f, ema_cs[t * 8 + u], 0.01f * (float)c[u]);
        ncs_out[t * 8 + u] = v;
        fs += v;
    }
    int inc = s;
#pragma unroll
    for (int off = 1; off < 64; off <<= 1) {
        const int n = __shfl_up(inc, off, 64);
        if (lane >= off) inc += n;
    }
#pragma unroll
    for (int off = 32; off > 0; off >>= 1) fs += __shfl_down(fs, off, 64);
    if (lane == 63) wsum[w] = inc;
    if (lane == 0)  red[w]  = fs;
    __syncthreads();
    if (t < 16) {
        int v = wsum[t];
#pragma unroll
        for (int off = 1; off < 16; off <<= 1) {
            const int n = __shfl_up(v, off, 64);
            if (t >= off) v += n;
        }
        wsum[t] = v;
        float fv = red[t];
#pragma unroll
        for (int off = 8; off > 0; off >>= 1) fv += __shfl_down(fv, off, 16);
        if (t == 0) *ntot = fv;
    }
    __syncthreads();
    int base = (w > 0 ? wsum[w - 1] : 0) + (inc - s);
#pragma unroll
    for (int u = 0; u < 8; ++u) { offsets[t * 8 + u] = base; base += c[u]; }
}

// ---------------------------------------------------------------- zq + loss partials + bucket scatter
__global__ void k_zq(const float* __restrict__ z, const float* __restrict__ emb,
                     const int* __restrict__ idx_i, const int* __restrict__ offsets,
                     int* __restrict__ cursor, int* __restrict__ buckets,
                     float* __restrict__ zq, float* __restrict__ losspart) {
    __shared__ float lred[4];
    const int t = threadIdx.x;
    const int wr = t >> 6, lane = t & 63;
    const int row = blockIdx.x * 4 + wr;
    const int code = idx_i[row];
    float4 zv = ((const float4*)z)[row * 64 + lane];
    float4 ev = ((const float4*)emb)[(size_t)code * 64 + lane];
    float4 o = make_float4(zv.x + (ev.x - zv.x), zv.y + (ev.y - zv.y),
                           zv.z + (ev.z - zv.z), zv.w + (ev.w - zv.w));
    ((float4*)zq)[row * 64 + lane] = o;
    float dx = ev.x - zv.x, dy = ev.y - zv.y, dz = ev.z - zv.z, dw = ev.w - zv.w;
    float s = fmaf(dx, dx, fmaf(dy, dy, fmaf(dz, dz, dw * dw)));
#pragma unroll
    for (int off = 32; off > 0; off >>= 1) s += __shfl_down(s, off, 64);
    if (lane == 0) {
        lred[wr] = s;
        const int pos = atomicAdd(&cursor[code], 1);
        buckets[offsets[code] + pos] = row;
    }
    __syncthreads();
    if (t == 0) losspart[blockIdx.x] = (lred[0] + lred[1]) + (lred[2] + lred[3]);
}

// ---------------------------------------------------------------- dw + new_ema_w + new_embedding (+loss tail block)
__global__ void k_dw_nemb(const float* __restrict__ z, const float* __restrict__ ema_w,
                          const int* __restrict__ counts, const int* __restrict__ offsets,
                          const int* __restrict__ buckets, const float* __restrict__ ncs,
                          const float* __restrict__ ntot_p, const float* __restrict__ losspart,
                          float* __restrict__ nemaw, float* __restrict__ nemb,
                          float* __restrict__ loss_out) {
    __shared__ float lred[4];
    if (blockIdx.x == K_CODES) {          // loss finalize
        const int t = threadIdx.x;        // 256
        float s = 0.0f;
        for (int i = t; i < 8192; i += 256) s += losspart[i];
#pragma unroll
        for (int off = 32; off > 0; off >>= 1) s += __shfl_down(s, off, 64);
        if ((t & 63) == 0) lred[t >> 6] = s;
        __syncthreads();
        if (t == 0)
            *loss_out = 0.25f * ((lred[0] + lred[1]) + (lred[2] + lred[3])) / 8388608.0f;
        return;
    }
    const int code = blockIdx.x;
    const int d    = threadIdx.x;         // 256 = DIM
    const int cnt  = counts[code];
    const int off  = offsets[code];
    float acc = 0.0f;
    for (int it = 0; it < cnt; ++it)
        acc += z[(size_t)buckets[off + it] * DIM + d];
    const float wv = fmaf(0.99f, ema_w[(size_t)code * DIM + d], 0.01f * acc);
    nemaw[(size_t)code * DIM + d] = wv;
    const float n  = *ntot_p;
    const float cs = (ncs[code] + 1e-5f) * (n / (n + (float)K_CODES * 1e-5f));
    nemb[(size_t)code * DIM + d] = wv / cs;
}

// ================================================================ fp32 fallback path (round-1 verified)
#define BM   64
#define BN   128
#define LSTR 36

__global__ void k_esq_zero_fb(const float* __restrict__ emb, float* __restrict__ esq,
                              float* __restrict__ zbuf) {
    const int gid  = blockIdx.x * blockDim.x + threadIdx.x;
    if (gid < K_CODES + 2) zbuf[gid] = 0.0f;
    const int code = gid >> 6;
    const int lane = gid & 63;
    float4 v = ((const float4*)emb)[code * 64 + lane];
    float s = fmaf(v.x, v.x, fmaf(v.y, v.y, fmaf(v.z, v.z, v.w * v.w)));
#pragma unroll
    for (int off = 32; off > 0; off >>= 1) s += __shfl_down(s, off, 64);
    if (lane == 0) esq[code] = s;
}

__global__ void k_init_nemaw_fb(const float* __restrict__ ema_w, float* __restrict__ out) {
    const int i = blockIdx.x * blockDim.x + threadIdx.x;
    float4 v = ((const float4*)ema_w)[i];
    ((float4*)out)[i] = make_float4(0.99f * v.x, 0.99f * v.y, 0.99f * v.z, 0.99f * v.w);
}

__global__ __launch_bounds__(256, 2) void k_argmin_fb(
        const float* __restrict__ z, const float* __restrict__ emb,
        const float* __restrict__ esq, int* __restrict__ idx_i, float* __restrict__ idx_f) {
    __shared__ float z_s[BM * LSTR];
    __shared__ float e_s[BN * LSTR];
    const int t = threadIdx.x, tx = t & 15, ty = t >> 4;
    const int row0 = blockIdx.x * BM;
    float best[4]; int bidx[4];
#pragma unroll
    for (int r = 0; r < 4; ++r) { best[r] = FLT_MAX; bidx[r] = 0; }
    for (int k0 = 0; k0 < K_CODES; k0 += BN) {
        float acc[4][8];
#pragma unroll
        for (int r = 0; r < 4; ++r)
#pragma unroll
            for (int c = 0; c < 8; ++c) acc[r][c] = 0.0f;
        for (int d0 = 0; d0 < DIM; d0 += 32) {
            __syncthreads();
#pragma unroll
            for (int i = 0; i < 2; ++i) {
                int f = i * 256 + t, r = f >> 3, c4 = (f & 7) << 2;
                *(float4*)&z_s[r * LSTR + c4] =
                    *(const float4*)(z + (size_t)(row0 + r) * DIM + d0 + c4);
            }
#pragma unroll
            for (int i = 0; i < 4; ++i) {
                int f = i * 256 + t, c = f >> 3, c4 = (f & 7) << 2;
                *(float4*)&e_s[c * LSTR + c4] =
                    *(const float4*)(emb + (size_t)(k0 + c) * DIM + d0 + c4);
            }
            __syncthreads();
#pragma unroll
            for (int dd = 0; dd < 32; dd += 4) {
                float4 a[4], b[8];
#pragma unroll
                for (int j = 0; j < 4; ++j)
                    a[j] = *(const float4*)&z_s[(ty * 4 + j) * LSTR + dd];
#pragma unroll
                for (int j = 0; j < 8; ++j)
                    b[j] = *(const float4*)&e_s[(tx + 16 * j) * LSTR + dd];
#pragma unroll
                for (int r = 0; r < 4; ++r)
#pragma unroll
                    for (int c = 0; c < 8; ++c) {
                        acc[r][c] = fmaf(a[r].x, b[c].x, acc[r][c]);
                        acc[r][c] = fmaf(a[r].y, b[c].y, acc[r][c]);
                        acc[r][c] = fmaf(a[r].z, b[c].z, acc[r][c]);
                        acc[r][c] = fmaf(a[r].w, b[c].w, acc[r][c]);
                    }
            }
        }
#pragma unroll
        for (int c = 0; c < 8; ++c) {
            const int code = k0 + tx + 16 * c;
            const float es = esq[code];
#pragma unroll
            for (int r = 0; r < 4; ++r) {
                float s = fmaf(-2.0f, acc[r][c], es);
                if (s < best[r] || (s == best[r] && code < bidx[r])) {
                    best[r] = s; bidx[r] = code;
                }
            }
        }
    }
    __syncthreads();
    float* rv = e_s; int* ri = (int*)z_s;
#pragma unroll
    for (int r = 0; r < 4; ++r) {
        rv[(ty * 4 + r) * 16 + tx] = best[r];
        ri[(ty * 4 + r) * 16 + tx] = bidx[r];
    }
    __syncthreads();
    if (t < 64) {
        float mv = rv[t * 16]; int mi = ri[t * 16];
#pragma unroll
        for (int i = 1; i < 16; ++i) {
            float v = rv[t * 16 + i]; int vi = ri[t * 16 + i];
            if (v < mv || (v == mv && vi < mi)) { mv = v; mi = vi; }
        }
        idx_i[row0 + t] = mi;
        idx_f[row0 + t] = (float)mi;
    }
}

__global__ void k_gather_fb(const float* __restrict__ z, const float* __restrict__ emb,
                            const int* __restrict__ idx_i, float* __restrict__ zq,
                            float* __restrict__ nemaw, float* __restrict__ counts,
                            float* __restrict__ loss) {
    const int gid  = blockIdx.x * blockDim.x + threadIdx.x;
    const int row  = gid >> 6;
    const int lane = gid & 63;
    const int code = idx_i[row];
    float4 zv = ((const float4*)z)[row * 64 + lane];
    float4 ev = ((const float4*)emb)[(size_t)code * 64 + lane];
    float4 o = make_float4(zv.x + (ev.x - zv.x), zv.y + (ev.y - zv.y),
                           zv.z + (ev.z - zv.z), zv.w + (ev.w - zv.w));
    ((float4*)zq)[row * 64 + lane] = o;
    float dx = ev.x - zv.x, dy = ev.y - zv.y, dz = ev.z - zv.z, dw = ev.w - zv.w;
    float s = fmaf(dx, dx, fmaf(dy, dy, fmaf(dz, dz, dw * dw)));
#pragma unroll
    for (int off = 32; off > 0; off >>= 1) s += __shfl_down(s, off, 64);
    if (lane == 0) { atomicAdd(loss, s); atomicAdd(&counts[code], 1.0f); }
    float* base = nemaw + (size_t)code * DIM + lane * 4;
    atomicAdd(base + 0, 0.01f * zv.x);
    atomicAdd(base + 1, 0.01f * zv.y);
    atomicAdd(base + 2, 0.01f * zv.z);
    atomicAdd(base + 3, 0.01f * zv.w);
}

__global__ void k_ncs_fb(const float* __restrict__ ema_cs, const float* __restrict__ counts,
                         float* __restrict__ ncs_out, float* __restrict__ ntot,
                         const float* __restrict__ loss_in, float* __restrict__ loss_out) {
    __shared__ float red[16];
    const int t = threadIdx.x;
    float s = 0.0f;
    for (int i = t; i < K_CODES; i += 1024) {
        float v = fmaf(0.99f, ema_cs[i], 0.01f * counts[i]);
        ncs_out[i] = v; s += v;
    }
#pragma unroll
    for (int off = 32; off > 0; off >>= 1) s += __shfl_down(s, off, 64);
    if ((t & 63) == 0) red[t >> 6] = s;
    __syncthreads();
    if (t < 16) {
        float v = red[t];
#pragma unroll
        for (int off = 8; off > 0; off >>= 1) v += __shfl_down(v, off, 16);
        if (t == 0) { *ntot = v; *loss_out = 0.25f * (*loss_in) / 8388608.0f; }
    }
}

__global__ void k_nemb_fb(const float* __restrict__ nemaw, const float* __restrict__ ncs,
                          const float* __restrict__ ntot_p, float* __restrict__ nemb) {
    const int i4 = blockIdx.x * blockDim.x + threadIdx.x;
    const int k  = i4 >> 6;
    const float n   = *ntot_p;
    const float inv = n / (n + (float)K_CODES * 1e-5f);
    const float cs  = (ncs[k] + 1e-5f) * inv;
    float4 wv = ((const float4*)nemaw)[i4];
    ((float4*)nemb)[i4] = make_float4(wv.x / cs, wv.y / cs, wv.z / cs, wv.w / cs);
}

extern "C" void kernel_launch(void* const* d_in, const int* in_sizes, int n_in,
                              void* d_out, int out_size, void* d_ws, size_t ws_size,
                              hipStream_t stream) {
    const float* z      = (const float*)d_in[0];
    const float* emb    = (const float*)d_in[1];
    const float* ema_cs = (const float*)d_in[2];
    const float* ema_w  = (const float*)d_in[3];
    float* out = (float*)d_out;
    char* wsb = (char*)d_ws;

    // ---- MFMA-path workspace layout (bytes), total 43,417,616
    unsigned short* zcat    = (unsigned short*)wsb;                  // 33,554,432
    unsigned short* ecat    = (unsigned short*)(wsb + 33554432);     //  8,388,608
    float*          part_v  = (float*)(wsb + 41943040);              //    524,288
    int*            part_i  = (int*)  (wsb + 42467328);              //    524,288
    float*          esq     = (float*)(wsb + 42991616);              //     32,768
    int*            ws_idx  = (int*)  (wsb + 43024384);              //    131,072
    int*            counts  = (int*)  (wsb + 43155456);              //     32,768
    int*            cursor  = (int*)  (wsb + 43188224);              //     32,768 (contiguous w/ counts)
    int*            offsets = (int*)  (wsb + 43220992);              //     32,768
    int*            buckets = (int*)  (wsb + 43253760);              //    131,072
    float*          lpart   = (float*)(wsb + 43384832);              //     32,768
    float*          ws_loss = (float*)(wsb + 43417600);
    float*          ws_ntot = ws_loss + 1;

    if (ws_size >= (size_t)43417616) {
        k_prep       <<<10240, 256, 0, stream>>>(z, emb, zcat, ecat, esq, counts);
        k_argmin_mfma<<<dim3(NROWS / 128, NCH), 256, 0, stream>>>(
            zcat, ecat, esq, part_v, part_i);
        k_reduce_part<<<NROWS / 256, 256, 0, stream>>>(part_v, part_i, ws_idx,
                                                       out + O_IDX, counts);
        k_scan_ncs   <<<1, 1024, 0, stream>>>(counts, ema_cs, offsets,
                                              out + O_NCS, ws_ntot);
        k_zq         <<<NROWS / 4, 256, 0, stream>>>(z, emb, ws_idx, offsets, cursor,
                                                     buckets, out + O_ZQ, lpart);
        k_dw_nemb    <<<K_CODES + 1, 256, 0, stream>>>(z, ema_w, counts, offsets, buckets,
                                                       out + O_NCS, ws_ntot, lpart,
                                                       out + O_NEMAW, out + O_NEMB,
                                                       out + O_LOSS);
    } else {
        // small-ws fallback (round-1 verified fp32 path)
        int*   f_idx    = (int*)wsb;
        float* f_counts = (float*)(wsb + 131072);
        float* f_loss   = f_counts + K_CODES;
        float* f_ntot   = f_loss + 1;
        float* f_esq    = (float*)(wsb + 163856);
        k_esq_zero_fb  <<<2048, 256, 0, stream>>>(emb, f_esq, f_counts);
        k_init_nemaw_fb<<<2048, 256, 0, stream>>>(ema_w, out + O_NEMAW);
        k_argmin_fb    <<<NROWS / BM, 256, 0, stream>>>(z, emb, f_esq, f_idx, out + O_IDX);
        k_gather_fb    <<<NROWS / 4, 256, 0, stream>>>(z, emb, f_idx, out + O_ZQ,
                                                       out + O_NEMAW, f_counts, f_loss);
        k_ncs_fb       <<<1, 1024, 0, stream>>>(ema_cs, f_counts, out + O_NCS, f_ntot,
                                                f_loss, out + O_LOSS);
        k_nemb_fb      <<<2048, 256, 0, stream>>>(out + O_NEMAW, out + O_NCS, f_ntot,
                                                  out + O_NEMB);
    }
}

// Round 5
// 633.228 us; speedup vs baseline: 4.5338x; 1.2089x over previous
//
#include <hip/hip_runtime.h>
#include <cfloat>

// VQ-VAE vector quantizer. Round 5: BN=256 (wave-tile 64x128, acc 4x8) cuts
// LDS traffic/FLOP to 0.75x; NCH=2 -> grid 512 = exactly 2 blocks/CU, no tail.
// N=32768 rows, K=8192 codes, D=256.
#define K_CODES 8192
#define DIM     256
#define NROWS   32768

// d_out float offsets (outputs concatenated in reference return order)
#define O_ZQ    0
#define O_LOSS  8388608
#define O_IDX   8388609
#define O_NEMB  8421377
#define O_NCS   10518529
#define O_NEMAW 10526721

// ---- MFMA path params
#define NCH          2                    // code chunks
#define CODES_PER_CH (K_CODES / NCH)      // 4096
#define NT_TILES     (CODES_PER_CH / 256) // 16

typedef __attribute__((ext_vector_type(8))) short short8;
typedef __attribute__((ext_vector_type(4))) float floatx4;

__device__ __forceinline__ unsigned short f2bf_rne(float x) {
    unsigned u = __float_as_uint(x);
    u += 0x7fffu + ((u >> 16) & 1u);
    return (unsigned short)(u >> 16);
}
__device__ __forceinline__ float bf2f(unsigned short h) {
    return __uint_as_float(((unsigned)h) << 16);
}
__device__ __forceinline__ void async16(const void* g, void* l) {
    __builtin_amdgcn_global_load_lds(
        (const __attribute__((address_space(1))) void*)g,
        (__attribute__((address_space(3))) void*)l, 16, 0, 0);
}

// ---------------------------------------------------------------- fused convert: z & emb -> {hi,lo} bf16 + |e|^2 + zero
__global__ void k_prep(const float* __restrict__ z, const float* __restrict__ emb,
                       unsigned short* __restrict__ zcat, unsigned short* __restrict__ ecat,
                       float* __restrict__ esq, int* __restrict__ zero16k) {
    const int b = blockIdx.x;
    if (b < 8192) {
        const int i = b * 256 + threadIdx.x;         // float4 idx, 2,097,152
        const int row = i >> 6;
        const int col = (i & 63) << 2;
        float4 v = ((const float4*)z)[i];
        // fold -2 into z: bf16(-2z) == -2*bf16(z) exactly (pow2 scale)
        float nx = -2.0f * v.x, ny = -2.0f * v.y, nz = -2.0f * v.z, nw = -2.0f * v.w;
        ushort4 h, l;
        h.x = f2bf_rne(nx); l.x = f2bf_rne(nx - bf2f(h.x));
        h.y = f2bf_rne(ny); l.y = f2bf_rne(ny - bf2f(h.y));
        h.z = f2bf_rne(nz); l.z = f2bf_rne(nz - bf2f(h.z));
        h.w = f2bf_rne(nw); l.w = f2bf_rne(nw - bf2f(h.w));
        *(ushort4*)&zcat[(size_t)row * 512 + col]       = h;
        *(ushort4*)&zcat[(size_t)row * 512 + 256 + col] = l;
    } else {
        const int gid  = (b - 8192) * 256 + threadIdx.x;  // 0..524287
        if (gid < 2 * K_CODES) zero16k[gid] = 0;          // counts + cursor
        const int code = gid >> 6;
        const int lane = gid & 63;
        const int col  = lane << 2;
        float4 v = ((const float4*)emb)[code * 64 + lane];
        ushort4 h, l;
        h.x = f2bf_rne(v.x); l.x = f2bf_rne(v.x - bf2f(h.x));
        h.y = f2bf_rne(v.y); l.y = f2bf_rne(v.y - bf2f(h.y));
        h.z = f2bf_rne(v.z); l.z = f2bf_rne(v.z - bf2f(h.z));
        h.w = f2bf_rne(v.w); l.w = f2bf_rne(v.w - bf2f(h.w));
        *(ushort4*)&ecat[(size_t)code * 512 + col]       = h;
        *(ushort4*)&ecat[(size_t)code * 512 + 256 + col] = l;
        float s = fmaf(v.x, v.x, fmaf(v.y, v.y, fmaf(v.z, v.z, v.w * v.w)));
#pragma unroll
        for (int off = 32; off > 0; off >>= 1) s += __shfl_down(s, off, 64);
        if (lane == 0) esq[code] = s;
    }
}

// ---------------------------------------------------------------- MFMA argmin GEMM (virtual K=768, BK=64, 128x256 tile)
// score(n,k) = esq[k] + dot(zcat_n, ecat_k segs), zcat encodes -2z.
// A segs {hi,hi,lo}: off_a=(k0&255)|((k0&512)>>1); B segs {hi,lo,hi}: off_b=k0&511.
// XOR-swizzled LDS (conflict-free, verified r4): logical (row R, 16B-chunk C)
// at ushort R*64 + ((C ^ (R&7))*8); staging permutes the global source per lane.
// 4 waves, wave-tile 64x128: wrow=(w>>1)*64, wcol=(w&1)*128, acc 4x8 of 16x16x32.
__global__ __launch_bounds__(256, 2) void k_argmin_mfma(
        const unsigned short* __restrict__ zcat, const unsigned short* __restrict__ ecat,
        const float* __restrict__ esq,
        float* __restrict__ part_v, int* __restrict__ part_i) {
    __shared__ __align__(16) unsigned short a_s[128 * 64];  // 16 KB
    __shared__ __align__(16) unsigned short b_s[256 * 64];  // 32 KB
    const int t    = threadIdx.x;
    const int w    = t >> 6;
    const int lane = t & 63;
    const int quad = lane >> 4;
    const int m    = lane & 15;
    const int wrow = (w >> 1) * 64;
    const int wcol = (w & 1) * 128;
    const int row0   = blockIdx.x * 128;
    const int cbase0 = blockIdx.y * CODES_PER_CH;
    // staging geometry: chunk = 8 rows x 128B; lane covers 16B (swizzled source)
    const int r8   = lane >> 3;
    const int cswz = ((lane & 7) ^ r8) * 8;
    const size_t aBase = (size_t)(row0 + r8) * 512 + cswz;
    const size_t bBase = (size_t)(cbase0 + r8) * 512 + cswz;
    // fragment-read swizzle offsets: half h chunk index = h*4+quad
    const int mx  = m & 7;
    const int xo0 = ((0 + quad) ^ mx) * 8;
    const int xo1 = ((4 + quad) ^ mx) * 8;

    float    best_v[16];
    unsigned best_p[4];     // per i: 4 reg-slots x 8-bit candidate (nt*8+j)
#pragma unroll
    for (int r = 0; r < 16; ++r) best_v[r] = FLT_MAX;
#pragma unroll
    for (int i = 0; i < 4; ++i) best_p[i] = 0u;

    for (int nt = 0; nt < NT_TILES; ++nt) {
        const int cb = cbase0 + nt * 256;
        floatx4 acc[4][8];
#pragma unroll
        for (int j = 0; j < 8; ++j) {
            const float es = esq[cb + wcol + j * 16 + m];
#pragma unroll
            for (int i = 0; i < 4; ++i)
                acc[i][j] = (floatx4){es, es, es, es};
        }

        for (int k0 = 0; k0 < 768; k0 += 64) {
            const int off_a = (k0 & 255) | ((k0 & 512) >> 1);
            const int off_b = k0 & 511;
            __syncthreads();   // prior iter's ds_reads done before overwrite
            // 48 chunks (16 A + 32 B) over 4 waves = 12 each
            const int u0 = w * 12;
#pragma unroll
            for (int c = 0; c < 12; ++c) {
                const int u = u0 + c;
                if (u < 16) {
                    async16(zcat + aBase + (size_t)u * (8 * 512) + off_a, &a_s[u * 512]);
                } else {
                    const int q = u - 16;
                    async16(ecat + bBase + (size_t)(nt * 256 + q * 8) * 512 + off_b,
                            &b_s[q * 512]);
                }
            }
            __syncthreads();   // barrier drains vmcnt(0): staged data visible
#pragma unroll
            for (int half = 0; half < 2; ++half) {
                const int xo = half ? xo1 : xo0;
                short8 af[4], bfr[8];
#pragma unroll
                for (int i = 0; i < 4; ++i)
                    af[i] = *(const short8*)&a_s[(wrow + i * 16 + m) * 64 + xo];
#pragma unroll
                for (int j = 0; j < 8; ++j)
                    bfr[j] = *(const short8*)&b_s[(wcol + j * 16 + m) * 64 + xo];
#pragma unroll
                for (int i = 0; i < 4; ++i)
#pragma unroll
                    for (int j = 0; j < 8; ++j)
                        acc[i][j] = __builtin_amdgcn_mfma_f32_16x16x32_bf16(
                            af[i], bfr[j], acc[i][j], 0, 0, 0);
            }
        }
        // epilogue: acc IS the score. codes ascend in (nt,j): strict < = first-min.
#pragma unroll
        for (int j = 0; j < 8; ++j) {
            const unsigned cand = (unsigned)(nt * 8 + j);   // 7 bits
#pragma unroll
            for (int i = 0; i < 4; ++i)
#pragma unroll
                for (int reg = 0; reg < 4; ++reg) {
                    const float s = acc[i][j][reg];
                    const int r = i * 4 + reg;
                    if (s < best_v[r]) {
                        best_v[r] = s;
                        best_p[i] = (best_p[i] & ~(255u << (reg * 8))) | (cand << (reg * 8));
                    }
                }
        }
    }
    // reconstruct codes, butterfly across the 16 lanes sharing each row
    __syncthreads();               // staging LDS free for reuse
    float* redv = (float*)a_s;     // [128][2]
    int*   redi = (int*)b_s;       // [128][2]
#pragma unroll
    for (int i = 0; i < 4; ++i)
#pragma unroll
        for (int reg = 0; reg < 4; ++reg) {
            const int r = i * 4 + reg;
            const unsigned b = (best_p[i] >> (reg * 8)) & 255u;
            float v  = best_v[r];
            int   bi = cbase0 + (int)(b >> 3) * 256 + wcol + (int)(b & 7) * 16 + m;
#pragma unroll
            for (int off = 1; off < 16; off <<= 1) {
                const float ov = __shfl_xor(v, off, 64);
                const int   oi = __shfl_xor(bi, off, 64);
                if (ov < v || (ov == v && oi < bi)) { v = ov; bi = oi; }
            }
            if (m == 0) {
                const int row = wrow + i * 16 + quad * 4 + reg;
                redv[row * 2 + (w & 1)] = v;
                redi[row * 2 + (w & 1)] = bi;
            }
        }
    __syncthreads();
    if (t < 128) {
        const float v0 = redv[t * 2], v1 = redv[t * 2 + 1];
        const int   i0 = redi[t * 2], i1 = redi[t * 2 + 1];
        const bool  b1 = (v1 < v0) || (v1 == v0 && i1 < i0);
        const size_t o = (size_t)blockIdx.y * NROWS + blockIdx.x * 128 + t;
        part_v[o] = b1 ? v1 : v0;
        part_i[o] = b1 ? i1 : i0;
    }
}

// ---------------------------------------------------------------- merge partials + histogram
__global__ void k_reduce_part(const float* __restrict__ pv, const int* __restrict__ pi,
                              int* __restrict__ idx_i, float* __restrict__ idx_f,
                              int* __restrict__ counts) {
    const int r = blockIdx.x * blockDim.x + threadIdx.x;
    float v = pv[r]; int bi = pi[r];
#pragma unroll
    for (int c = 1; c < NCH; ++c) {
        const float v2 = pv[(size_t)c * NROWS + r];
        const int   i2 = pi[(size_t)c * NROWS + r];
        if (v2 < v || (v2 == v && i2 < bi)) { v = v2; bi = i2; }
    }
    idx_i[r] = bi;
    idx_f[r] = (float)bi;
    atomicAdd(&counts[bi], 1);
}

// ---------------------------------------------------------------- scan + new_cluster_size + n  (1 block, 1024 thr)
__global__ void k_scan_ncs(const int* __restrict__ counts, const float* __restrict__ ema_cs,
                           int* __restrict__ offsets, float* __restrict__ ncs_out,
                           float* __restrict__ ntot) {
    __shared__ int   wsum[16];
    __shared__ float red[16];
    const int t = threadIdx.x;
    const int lane = t & 63, w = t >> 6;
    int c[8]; int s = 0; float fs = 0.0f;
#pragma unroll
    for (int u = 0; u < 8; ++u) {
        c[u] = counts[t * 8 + u]; s += c[u];
        const float v = fmaf(0.99f, ema_cs[t * 8 + u], 0.01f * (float)c[u]);
        ncs_out[t * 8 + u] = v;
        fs += v;
    }
    int inc = s;
#pragma unroll
    for (int off = 1; off < 64; off <<= 1) {
        const int n = __shfl_up(inc, off, 64);
        if (lane >= off) inc += n;
    }
#pragma unroll
    for (int off = 32; off > 0; off >>= 1) fs += __shfl_down(fs, off, 64);
    if (lane == 63) wsum[w] = inc;
    if (lane == 0)  red[w]  = fs;
    __syncthreads();
    if (t < 16) {
        int v = wsum[t];
#pragma unroll
        for (int off = 1; off < 16; off <<= 1) {
            const int n = __shfl_up(v, off, 64);
            if (t >= off) v += n;
        }
        wsum[t] = v;
        float fv = red[t];
#pragma unroll
        for (int off = 8; off > 0; off >>= 1) fv += __shfl_down(fv, off, 16);
        if (t == 0) *ntot = fv;
    }
    __syncthreads();
    int base = (w > 0 ? wsum[w - 1] : 0) + (inc - s);
#pragma unroll
    for (int u = 0; u < 8; ++u) { offsets[t * 8 + u] = base; base += c[u]; }
}

// ---------------------------------------------------------------- zq + loss partials + bucket scatter
__global__ void k_zq(const float* __restrict__ z, const float* __restrict__ emb,
                     const int* __restrict__ idx_i, const int* __restrict__ offsets,
                     int* __restrict__ cursor, int* __restrict__ buckets,
                     float* __restrict__ zq, float* __restrict__ losspart) {
    __shared__ float lred[4];
    const int t = threadIdx.x;
    const int wr = t >> 6, lane = t & 63;
    const int row = blockIdx.x * 4 + wr;
    const int code = idx_i[row];
    float4 zv = ((const float4*)z)[row * 64 + lane];
    float4 ev = ((const float4*)emb)[(size_t)code * 64 + lane];
    float4 o = make_float4(zv.x + (ev.x - zv.x), zv.y + (ev.y - zv.y),
                           zv.z + (ev.z - zv.z), zv.w + (ev.w - zv.w));
    ((float4*)zq)[row * 64 + lane] = o;
    float dx = ev.x - zv.x, dy = ev.y - zv.y, dz = ev.z - zv.z, dw = ev.w - zv.w;
    float s = fmaf(dx, dx, fmaf(dy, dy, fmaf(dz, dz, dw * dw)));
#pragma unroll
    for (int off = 32; off > 0; off >>= 1) s += __shfl_down(s, off, 64);
    if (lane == 0) {
        lred[wr] = s;
        const int pos = atomicAdd(&cursor[code], 1);
        buckets[offsets[code] + pos] = row;
    }
    __syncthreads();
    if (t == 0) losspart[blockIdx.x] = (lred[0] + lred[1]) + (lred[2] + lred[3]);
}

// ---------------------------------------------------------------- dw + new_ema_w + new_embedding (+loss tail block)
__global__ void k_dw_nemb(const float* __restrict__ z, const float* __restrict__ ema_w,
                          const int* __restrict__ counts, const int* __restrict__ offsets,
                          const int* __restrict__ buckets, const float* __restrict__ ncs,
                          const float* __restrict__ ntot_p, const float* __restrict__ losspart,
                          float* __restrict__ nemaw, float* __restrict__ nemb,
                          float* __restrict__ loss_out) {
    __shared__ float lred[4];
    if (blockIdx.x == K_CODES) {          // loss finalize
        const int t = threadIdx.x;        // 256
        float s = 0.0f;
        for (int i = t; i < 8192; i += 256) s += losspart[i];
#pragma unroll
        for (int off = 32; off > 0; off >>= 1) s += __shfl_down(s, off, 64);
        if ((t & 63) == 0) lred[t >> 6] = s;
        __syncthreads();
        if (t == 0)
            *loss_out = 0.25f * ((lred[0] + lred[1]) + (lred[2] + lred[3])) / 8388608.0f;
        return;
    }
    const int code = blockIdx.x;
    const int d    = threadIdx.x;         // 256 = DIM
    const int cnt  = counts[code];
    const int off  = offsets[code];
    float acc = 0.0f;
    for (int it = 0; it < cnt; ++it)
        acc += z[(size_t)buckets[off + it] * DIM + d];
    const float wv = fmaf(0.99f, ema_w[(size_t)code * DIM + d], 0.01f * acc);
    nemaw[(size_t)code * DIM + d] = wv;
    const float n  = *ntot_p;
    const float cs = (ncs[code] + 1e-5f) * (n / (n + (float)K_CODES * 1e-5f));
    nemb[(size_t)code * DIM + d] = wv / cs;
}

// ================================================================ fp32 fallback path (round-1 verified)
#define BM   64
#define BN   128
#define LSTR 36

__global__ void k_esq_zero_fb(const float* __restrict__ emb, float* __restrict__ esq,
                              float* __restrict__ zbuf) {
    const int gid  = blockIdx.x * blockDim.x + threadIdx.x;
    if (gid < K_CODES + 2) zbuf[gid] = 0.0f;
    const int code = gid >> 6;
    const int lane = gid & 63;
    float4 v = ((const float4*)emb)[code * 64 + lane];
    float s = fmaf(v.x, v.x, fmaf(v.y, v.y, fmaf(v.z, v.z, v.w * v.w)));
#pragma unroll
    for (int off = 32; off > 0; off >>= 1) s += __shfl_down(s, off, 64);
    if (lane == 0) esq[code] = s;
}

__global__ void k_init_nemaw_fb(const float* __restrict__ ema_w, float* __restrict__ out) {
    const int i = blockIdx.x * blockDim.x + threadIdx.x;
    float4 v = ((const float4*)ema_w)[i];
    ((float4*)out)[i] = make_float4(0.99f * v.x, 0.99f * v.y, 0.99f * v.z, 0.99f * v.w);
}

__global__ __launch_bounds__(256, 2) void k_argmin_fb(
        const float* __restrict__ z, const float* __restrict__ emb,
        const float* __restrict__ esq, int* __restrict__ idx_i, float* __restrict__ idx_f) {
    __shared__ float z_s[BM * LSTR];
    __shared__ float e_s[BN * LSTR];
    const int t = threadIdx.x, tx = t & 15, ty = t >> 4;
    const int row0 = blockIdx.x * BM;
    float best[4]; int bidx[4];
#pragma unroll
    for (int r = 0; r < 4; ++r) { best[r] = FLT_MAX; bidx[r] = 0; }
    for (int k0 = 0; k0 < K_CODES; k0 += BN) {
        float acc[4][8];
#pragma unroll
        for (int r = 0; r < 4; ++r)
#pragma unroll
            for (int c = 0; c < 8; ++c) acc[r][c] = 0.0f;
        for (int d0 = 0; d0 < DIM; d0 += 32) {
            __syncthreads();
#pragma unroll
            for (int i = 0; i < 2; ++i) {
                int f = i * 256 + t, r = f >> 3, c4 = (f & 7) << 2;
                *(float4*)&z_s[r * LSTR + c4] =
                    *(const float4*)(z + (size_t)(row0 + r) * DIM + d0 + c4);
            }
#pragma unroll
            for (int i = 0; i < 4; ++i) {
                int f = i * 256 + t, c = f >> 3, c4 = (f & 7) << 2;
                *(float4*)&e_s[c * LSTR + c4] =
                    *(const float4*)(emb + (size_t)(k0 + c) * DIM + d0 + c4);
            }
            __syncthreads();
#pragma unroll
            for (int dd = 0; dd < 32; dd += 4) {
                float4 a[4], b[8];
#pragma unroll
                for (int j = 0; j < 4; ++j)
                    a[j] = *(const float4*)&z_s[(ty * 4 + j) * LSTR + dd];
#pragma unroll
                for (int j = 0; j < 8; ++j)
                    b[j] = *(const float4*)&e_s[(tx + 16 * j) * LSTR + dd];
#pragma unroll
                for (int r = 0; r < 4; ++r)
#pragma unroll
                    for (int c = 0; c < 8; ++c) {
                        acc[r][c] = fmaf(a[r].x, b[c].x, acc[r][c]);
                        acc[r][c] = fmaf(a[r].y, b[c].y, acc[r][c]);
                        acc[r][c] = fmaf(a[r].z, b[c].z, acc[r][c]);
                        acc[r][c] = fmaf(a[r].w, b[c].w, acc[r][c]);
                    }
            }
        }
#pragma unroll
        for (int c = 0; c < 8; ++c) {
            const int code = k0 + tx + 16 * c;
            const float es = esq[code];
#pragma unroll
            for (int r = 0; r < 4; ++r) {
                float s = fmaf(-2.0f, acc[r][c], es);
                if (s < best[r] || (s == best[r] && code < bidx[r])) {
                    best[r] = s; bidx[r] = code;
                }
            }
        }
    }
    __syncthreads();
    float* rv = e_s; int* ri = (int*)z_s;
#pragma unroll
    for (int r = 0; r < 4; ++r) {
        rv[(ty * 4 + r) * 16 + tx] = best[r];
        ri[(ty * 4 + r) * 16 + tx] = bidx[r];
    }
    __syncthreads();
    if (t < 64) {
        float mv = rv[t * 16]; int mi = ri[t * 16];
#pragma unroll
        for (int i = 1; i < 16; ++i) {
            float v = rv[t * 16 + i]; int vi = ri[t * 16 + i];
            if (v < mv || (v == mv && vi < mi)) { mv = v; mi = vi; }
        }
        idx_i[row0 + t] = mi;
        idx_f[row0 + t] = (float)mi;
    }
}

__global__ void k_gather_fb(const float* __restrict__ z, const float* __restrict__ emb,
                            const int* __restrict__ idx_i, float* __restrict__ zq,
                            float* __restrict__ nemaw, float* __restrict__ counts,
                            float* __restrict__ loss) {
    const int gid  = blockIdx.x * blockDim.x + threadIdx.x;
    const int row  = gid >> 6;
    const int lane = gid & 63;
    const int code = idx_i[row];
    float4 zv = ((const float4*)z)[row * 64 + lane];
    float4 ev = ((const float4*)emb)[(size_t)code * 64 + lane];
    float4 o = make_float4(zv.x + (ev.x - zv.x), zv.y + (ev.y - zv.y),
                           zv.z + (ev.z - zv.z), zv.w + (ev.w - zv.w));
    ((float4*)zq)[row * 64 + lane] = o;
    float dx = ev.x - zv.x, dy = ev.y - zv.y, dz = ev.z - zv.z, dw = ev.w - zv.w;
    float s = fmaf(dx, dx, fmaf(dy, dy, fmaf(dz, dz, dw * dw)));
#pragma unroll
    for (int off = 32; off > 0; off >>= 1) s += __shfl_down(s, off, 64);
    if (lane == 0) { atomicAdd(loss, s); atomicAdd(&counts[code], 1.0f); }
    float* base = nemaw + (size_t)code * DIM + lane * 4;
    atomicAdd(base + 0, 0.01f * zv.x);
    atomicAdd(base + 1, 0.01f * zv.y);
    atomicAdd(base + 2, 0.01f * zv.z);
    atomicAdd(base + 3, 0.01f * zv.w);
}

__global__ void k_ncs_fb(const float* __restrict__ ema_cs, const float* __restrict__ counts,
                         float* __restrict__ ncs_out, float* __restrict__ ntot,
                         const float* __restrict__ loss_in, float* __restrict__ loss_out) {
    __shared__ float red[16];
    const int t = threadIdx.x;
    float s = 0.0f;
    for (int i = t; i < K_CODES; i += 1024) {
        float v = fmaf(0.99f, ema_cs[i], 0.01f * counts[i]);
        ncs_out[i] = v; s += v;
    }
#pragma unroll
    for (int off = 32; off > 0; off >>= 1) s += __shfl_down(s, off, 64);
    if ((t & 63) == 0) red[t >> 6] = s;
    __syncthreads();
    if (t < 16) {
        float v = red[t];
#pragma unroll
        for (int off = 8; off > 0; off >>= 1) v += __shfl_down(v, off, 16);
        if (t == 0) { *ntot = v; *loss_out = 0.25f * (*loss_in) / 8388608.0f; }
    }
}

__global__ void k_nemb_fb(const float* __restrict__ nemaw, const float* __restrict__ ncs,
                          const float* __restrict__ ntot_p, float* __restrict__ nemb) {
    const int i4 = blockIdx.x * blockDim.x + threadIdx.x;
    const int k  = i4 >> 6;
    const float n   = *ntot_p;
    const float inv = n / (n + (float)K_CODES * 1e-5f);
    const float cs  = (ncs[k] + 1e-5f) * inv;
    float4 wv = ((const float4*)nemaw)[i4];
    ((float4*)nemb)[i4] = make_float4(wv.x / cs, wv.y / cs, wv.z / cs, wv.w / cs);
}

extern "C" void kernel_launch(void* const* d_in, const int* in_sizes, int n_in,
                              void* d_out, int out_size, void* d_ws, size_t ws_size,
                              hipStream_t stream) {
    const float* z      = (const float*)d_in[0];
    const float* emb    = (const float*)d_in[1];
    const float* ema_cs = (const float*)d_in[2];
    const float* ema_w  = (const float*)d_in[3];
    float* out = (float*)d_out;
    char* wsb = (char*)d_ws;

    // ---- MFMA-path workspace layout (bytes), total 43,417,616 (NCH=2 uses
    // only half of part_v/part_i but offsets kept from r3 layout)
    unsigned short* zcat    = (unsigned short*)wsb;                  // 33,554,432
    unsigned short* ecat    = (unsigned short*)(wsb + 33554432);     //  8,388,608
    float*          part_v  = (float*)(wsb + 41943040);              //    524,288
    int*            part_i  = (int*)  (wsb + 42467328);              //    524,288
    float*          esq     = (float*)(wsb + 42991616);              //     32,768
    int*            ws_idx  = (int*)  (wsb + 43024384);              //    131,072
    int*            counts  = (int*)  (wsb + 43155456);              //     32,768
    int*            cursor  = (int*)  (wsb + 43188224);              //     32,768 (contiguous w/ counts)
    int*            offsets = (int*)  (wsb + 43220992);              //     32,768
    int*            buckets = (int*)  (wsb + 43253760);              //    131,072
    float*          lpart   = (float*)(wsb + 43384832);              //     32,768
    float*          ws_loss = (float*)(wsb + 43417600);
    float*          ws_ntot = ws_loss + 1;

    if (ws_size >= (size_t)43417616) {
        k_prep       <<<10240, 256, 0, stream>>>(z, emb, zcat, ecat, esq, counts);
        k_argmin_mfma<<<dim3(NROWS / 128, NCH), 256, 0, stream>>>(
            zcat, ecat, esq, part_v, part_i);
        k_reduce_part<<<NROWS / 256, 256, 0, stream>>>(part_v, part_i, ws_idx,
                                                       out + O_IDX, counts);
        k_scan_ncs   <<<1, 1024, 0, stream>>>(counts, ema_cs, offsets,
                                              out + O_NCS, ws_ntot);
        k_zq         <<<NROWS / 4, 256, 0, stream>>>(z, emb, ws_idx, offsets, cursor,
                                                     buckets, out + O_ZQ, lpart);
        k_dw_nemb    <<<K_CODES + 1, 256, 0, stream>>>(z, ema_w, counts, offsets, buckets,
                                                       out + O_NCS, ws_ntot, lpart,
                                                       out + O_NEMAW, out + O_NEMB,
                                                       out + O_LOSS);
    } else {
        // small-ws fallback (round-1 verified fp32 path)
        int*   f_idx    = (int*)wsb;
        float* f_counts = (float*)(wsb + 131072);
        float* f_loss   = f_counts + K_CODES;
        float* f_ntot   = f_loss + 1;
        float* f_esq    = (float*)(wsb + 163856);
        k_esq_zero_fb  <<<2048, 256, 0, stream>>>(emb, f_esq, f_counts);
        k_init_nemaw_fb<<<2048, 256, 0, stream>>>(ema_w, out + O_NEMAW);
        k_argmin_fb    <<<NROWS / BM, 256, 0, stream>>>(z, emb, f_esq, f_idx, out + O_IDX);
        k_gather_fb    <<<NROWS / 4, 256, 0, stream>>>(z, emb, f_idx, out + O_ZQ,
                                                       out + O_NEMAW, f_counts, f_loss);
        k_ncs_fb       <<<1, 1024, 0, stream>>>(ema_cs, f_counts, out + O_NCS, f_ntot,
                                                f_loss, out + O_LOSS);
        k_nemb_fb      <<<2048, 256, 0, stream>>>(out + O_NEMAW, out + O_NCS, f_ntot,
                                                  out + O_NEMB);
    }
}